// Round 3
// baseline (950.419 us; speedup 1.0000x reference)
//
#include <hip/hip_runtime.h>
#include <hip/hip_bf16.h>
#include <cstdint>

typedef unsigned short us;
typedef __attribute__((ext_vector_type(4))) float f32x4;
typedef __attribute__((ext_vector_type(8))) short bf16x8;
typedef __attribute__((ext_vector_type(4))) short s16x4;
typedef __attribute__((ext_vector_type(8))) short s16x8;

__device__ __forceinline__ float b2f(us s){
  union { float f; unsigned u; } x; x.u = ((unsigned)s) << 16; return x.f;
}
__device__ __forceinline__ us f2b(float f){
  union { float f; unsigned u; } x; x.f = f;
  unsigned r = x.u + 0x7FFFu + ((x.u >> 16) & 1u);
  return (us)(r >> 16);
}

#define GLDS16(gp, lp) __builtin_amdgcn_global_load_lds( \
    (const __attribute__((address_space(1))) void*)(gp), \
    (__attribute__((address_space(3))) void*)(lp), 16, 0, 0)

// ---------------------------------------------------------------------------
// dtype detector: flag=1 -> inputs fp32, flag=0 -> inputs bf16. (Round-2
// evidence: fp32.) Bits 14..7 of a word are a bf16 exponent iff data is bf16.
// ---------------------------------------------------------------------------
__global__ void detect_kernel(const unsigned* __restrict__ xw, int* __restrict__ flag){
  __shared__ int cnt;
  if (threadIdx.x == 0) cnt = 0;
  __syncthreads();
  int c = 0;
  for (int i = threadIdx.x; i < 1024; i += 256){
    const unsigned e = (xw[i] >> 7) & 0xFF;
    if (e >= 100 && e <= 140) ++c;
  }
  atomicAdd(&cnt, c);
  __syncthreads();
  if (threadIdx.x == 0) *flag = (cnt < 512) ? 1 : 0;
}

// ---------------------------------------------------------------------------
// Plain GEMM: C[M,N] = A[M,K] @ BT[N,K]^T (+bias)(+silu). 128x128 tile, BK=32,
// 4 waves, mfma_f32_16x16x32_bf16, global_load_lds width=16.
// ---------------------------------------------------------------------------
template<bool OUT_BF16, bool SILU>
__global__ __launch_bounds__(256, 2)
void gemm_plain(const us* __restrict__ A, int lda,
                const us* __restrict__ BT, int ldb,
                void* __restrict__ Cout, int ldc,
                const us* __restrict__ bias,
                int M, int N, int K, int Nvalid)
{
  __shared__ us As[128*32];
  __shared__ us Bs[128*32];
  const int bm = blockIdx.y * 128, bn = blockIdx.x * 128;
  const int tid = threadIdx.x, wave = tid >> 6, lane = tid & 63;
  const int llo = lane & 15, lhi = lane >> 4;

  const us* aP[2]; const us* bP[2]; us* lA[2]; us* lB[2];
#pragma unroll
  for (int s = 0; s < 2; ++s){
    const int chunk = s*256 + wave*64 + lane;
    const int r = chunk >> 2, cc = chunk & 3;
    aP[s] = A  + (size_t)(bm + r) * lda + cc*8;
    bP[s] = BT + (size_t)(bn + r) * ldb + cc*8;
    lA[s] = As + (size_t)(s*256 + wave*64) * 8;  // wave-uniform base
    lB[s] = Bs + (size_t)(s*256 + wave*64) * 8;
  }

  f32x4 acc[4][4] = {};
  const int waveM = (wave >> 1) * 64, waveN = (wave & 1) * 64;

  for (int k0 = 0; k0 < K; k0 += 32){
    GLDS16(aP[0] + k0, lA[0]);
    GLDS16(aP[1] + k0, lA[1]);
    GLDS16(bP[0] + k0, lB[0]);
    GLDS16(bP[1] + k0, lB[1]);
    __syncthreads();
    bf16x8 af[4], bv[4];
#pragma unroll
    for (int t = 0; t < 4; ++t){
      af[t] = *reinterpret_cast<const bf16x8*>(As + (waveM + t*16 + llo)*32 + lhi*8);
      bv[t] = *reinterpret_cast<const bf16x8*>(Bs + (waveN + t*16 + llo)*32 + lhi*8);
    }
#pragma unroll
    for (int mt = 0; mt < 4; ++mt)
#pragma unroll
      for (int nt = 0; nt < 4; ++nt)
        acc[mt][nt] = __builtin_amdgcn_mfma_f32_16x16x32_bf16(af[mt], bv[nt], acc[mt][nt], 0, 0, 0);
    __syncthreads();
  }

#pragma unroll
  for (int nt = 0; nt < 4; ++nt){
    const int col = bn + waveN + nt*16 + llo;
    float bb = 0.f;
    if (bias && col < Nvalid) bb = b2f(bias[col]);
#pragma unroll
    for (int mt = 0; mt < 4; ++mt){
      const int row0 = bm + waveM + mt*16 + lhi*4;  // C/D: col=lane&15, row=quad*4+reg
#pragma unroll
      for (int r = 0; r < 4; ++r){
        if (col < Nvalid){
          float v = acc[mt][nt][r] + bb;
          if (SILU) v = v / (1.f + __expf(-v));
          if (OUT_BF16) ((us*)Cout)[(size_t)(row0 + r) * ldc + col] = f2b(v);
          else          ((float*)Cout)[(size_t)(row0 + r) * ldc + col] = v;
        }
      }
    }
  }
}

// ---------------------------------------------------------------------------
// Grouped (MoE) GEMM over position space. blockIdx.z = expert.
// ---------------------------------------------------------------------------
template<bool OUT_BF16, bool SILU>
__global__ __launch_bounds__(256, 2)
void gemm_group(const us* __restrict__ Abase, int lda,
                const int* __restrict__ rowmap,
                const int* __restrict__ offsets,   // [E+1], offsets[E]=8192
                const us* __restrict__ BTbase,     // [E][N][K]
                void* __restrict__ Cout, int ldc,
                const us* __restrict__ biasbase,   // [E][N]
                int N, int K)
{
  const int e   = blockIdx.z;
  const int off = offsets[e];
  const int Te  = offsets[e + 1] - off;
  const int bmL = blockIdx.y * 128;
  if (bmL >= Te) return;

  __shared__ us As[128*32];
  __shared__ us Bs[128*32];
  const us* BT   = BTbase  + (size_t)e * N * K;
  const us* bias = biasbase + (size_t)e * N;
  const int bn = blockIdx.x * 128;
  const int tid = threadIdx.x, wave = tid >> 6, lane = tid & 63;
  const int llo = lane & 15, lhi = lane >> 4;

  const us* aP[2]; const us* bP[2]; us* lA[2]; us* lB[2];
#pragma unroll
  for (int s = 0; s < 2; ++s){
    const int chunk = s*256 + wave*64 + lane;
    const int r = chunk >> 2, cc = chunk & 3;
    int pos = off + bmL + r; if (pos > 8191) pos = 8191; // OOB rows masked on store
    const int arow = rowmap ? rowmap[pos] : pos;
    aP[s] = Abase + (size_t)arow * lda + cc*8;
    bP[s] = BT + (size_t)(bn + r) * K + cc*8;
    lA[s] = As + (size_t)(s*256 + wave*64) * 8;
    lB[s] = Bs + (size_t)(s*256 + wave*64) * 8;
  }

  f32x4 acc[4][4] = {};
  const int waveM = (wave >> 1) * 64, waveN = (wave & 1) * 64;

  for (int k0 = 0; k0 < K; k0 += 32){
    GLDS16(aP[0] + k0, lA[0]);
    GLDS16(aP[1] + k0, lA[1]);
    GLDS16(bP[0] + k0, lB[0]);
    GLDS16(bP[1] + k0, lB[1]);
    __syncthreads();
    bf16x8 af[4], bv[4];
#pragma unroll
    for (int t = 0; t < 4; ++t){
      af[t] = *reinterpret_cast<const bf16x8*>(As + (waveM + t*16 + llo)*32 + lhi*8);
      bv[t] = *reinterpret_cast<const bf16x8*>(Bs + (waveN + t*16 + llo)*32 + lhi*8);
    }
#pragma unroll
    for (int mt = 0; mt < 4; ++mt)
#pragma unroll
      for (int nt = 0; nt < 4; ++nt)
        acc[mt][nt] = __builtin_amdgcn_mfma_f32_16x16x32_bf16(af[mt], bv[nt], acc[mt][nt], 0, 0, 0);
    __syncthreads();
  }

#pragma unroll
  for (int nt = 0; nt < 4; ++nt){
    const int col = bn + waveN + nt*16 + llo;
    const float bb = b2f(bias[col]);
#pragma unroll
    for (int mt = 0; mt < 4; ++mt){
      const int localBase = bmL + waveM + mt*16 + lhi*4;
#pragma unroll
      for (int r = 0; r < 4; ++r){
        const int local = localBase + r;
        if (local < Te){
          float v = acc[mt][nt][r] + bb;
          if (SILU) v = v / (1.f + __expf(-v));
          const size_t row = (size_t)(off + local);
          if (OUT_BF16) ((us*)Cout)[row * ldc + col] = f2b(v);
          else          ((float*)Cout)[row * ldc + col] = v;
        }
      }
    }
  }
}

// ---------------------------------------------------------------------------
// [R,C] -> bf16 [Cp,R] transpose; src fp32 (flag=1) or bf16 (flag=0).
// ---------------------------------------------------------------------------
__global__ void transpose_any(const void* __restrict__ src_, us* __restrict__ dst,
                              int R, int C, long long smat, long long dmat,
                              const int* __restrict__ flag)
{
  const int f32 = *flag;
  dst += (size_t)blockIdx.z * dmat;
  __shared__ us tile[32][33];
  const int c0 = blockIdx.x * 32, r0 = blockIdx.y * 32;
  const int tx = threadIdx.x & 31, ty = threadIdx.x >> 5;  // 32x8
#pragma unroll
  for (int i = 0; i < 4; ++i){
    const int r = r0 + ty + i*8, c = c0 + tx;
    const size_t idx = (size_t)blockIdx.z * smat + (size_t)r * C + c;
    us v = 0;
    if (c < C){
      if (f32) v = f2b(((const float*)src_)[idx]);
      else     v = ((const us*)src_)[idx];
    }
    tile[ty + i*8][tx] = v;
  }
  __syncthreads();
#pragma unroll
  for (int i = 0; i < 4; ++i){
    const int dr = c0 + ty + i*8;
    dst[(size_t)dr * R + r0 + tx] = tile[tx][ty + i*8];
  }
}

__global__ void cvt_any_bf(const void* __restrict__ src, us* __restrict__ dst, int n,
                           const int* __restrict__ flag){
  const int i = (blockIdx.x * 256 + threadIdx.x) * 4;
  if (i >= n) return;
  s16x4 o;
  if (*flag){
    f32x4 v = *reinterpret_cast<const f32x4*>((const float*)src + i);
#pragma unroll
    for (int k = 0; k < 4; ++k) o[k] = (short)f2b(v[k]);
  } else {
    o = *reinterpret_cast<const s16x4*>((const us*)src + i);
  }
  *reinterpret_cast<s16x4*>(dst + i) = o;
}

// ---------------------------------------------------------------------------
// Router fidelity path (all fp32): M = Wproj @ Wg  [512,8]; one wave per row.
// ---------------------------------------------------------------------------
__global__ void compose_router(const void* __restrict__ Wproj, const void* __restrict__ Wg,
                               float* __restrict__ M, const int* __restrict__ flag)
{
  const int f32 = *flag;
  const int wave = threadIdx.x >> 6, lane = threadIdx.x & 63;
  const int d = blockIdx.x * 4 + wave;   // 128 blocks * 4 waves = 512 rows
  float acc[8] = {0,0,0,0,0,0,0,0};
  for (int n = lane; n < 1024; n += 64){
    float wp;
    if (f32) wp = ((const float*)Wproj)[(size_t)d * 1024 + n];
    else     wp = b2f(((const us*)Wproj)[(size_t)d * 1024 + n]);
    if (f32){
      const float* wg = (const float*)Wg + (size_t)n * 8;
#pragma unroll
      for (int e = 0; e < 8; ++e) acc[e] += wp * wg[e];
    } else {
      const s16x8 wg = *reinterpret_cast<const s16x8*>((const us*)Wg + (size_t)n * 8);
#pragma unroll
      for (int e = 0; e < 8; ++e) acc[e] += wp * b2f((us)wg[e]);
    }
  }
#pragma unroll
  for (int e = 0; e < 8; ++e){
    float v = acc[e];
    for (int off = 32; off > 0; off >>= 1) v += __shfl_down(v, off);
    if (lane == 0) M[(size_t)d * 8 + e] = v;
  }
}

// logits[t] = x[t] @ M (fp32); top-2 + sigmoid gates + expert counts.
__global__ void router2(const void* __restrict__ x, const float* __restrict__ M,
                        int* __restrict__ eidx, float* __restrict__ gates,
                        int* __restrict__ counts, const int* __restrict__ flag)
{
  const int f32 = *flag;
  const int wave = threadIdx.x >> 6, lane = threadIdx.x & 63;
  const int t = blockIdx.x * 4 + wave;
  float l[8] = {0,0,0,0,0,0,0,0};
  for (int d = lane; d < 512; d += 64){
    float xv;
    if (f32) xv = ((const float*)x)[(size_t)t * 512 + d];
    else     xv = b2f(((const us*)x)[(size_t)t * 512 + d]);
    const float* mr = M + (size_t)d * 8;
#pragma unroll
    for (int e = 0; e < 8; ++e) l[e] += xv * mr[e];
  }
#pragma unroll
  for (int e = 0; e < 8; ++e){
    float v = l[e];
    for (int off = 32; off > 0; off >>= 1) v += __shfl_down(v, off);
    l[e] = v;
  }
  if (lane == 0){
    int e0 = 0; float v0 = l[0];
#pragma unroll
    for (int e = 1; e < 8; ++e) if (l[e] > v0){ v0 = l[e]; e0 = e; }
    int e1 = (e0 == 0) ? 1 : 0; float v1 = l[e1];
#pragma unroll
    for (int e = 0; e < 8; ++e) if (e != e0 && l[e] > v1){ v1 = l[e]; e1 = e; }
    const float g1 = 1.f / (1.f + __expf(v0 - v1));   // gate of 2nd expert
    eidx[t*2] = e0;  eidx[t*2+1] = e1;
    gates[t*2] = 1.f - g1; gates[t*2+1] = g1;
    atomicAdd(&counts[e0], 1); atomicAdd(&counts[e1], 1);
  }
}

__global__ void scan_kernel(const int* __restrict__ counts, int* __restrict__ offsets){
  if (threadIdx.x == 0){
    int s = 0;
    for (int e = 0; e < 8; ++e){ offsets[e] = s; s += counts[e]; }
    offsets[8] = s;
  }
}

__global__ void fill_kernel(const int* __restrict__ eidx, const int* __restrict__ offsets,
                            int* __restrict__ fill, int* __restrict__ pos_tk,
                            int* __restrict__ tok_of_pos){
  const int i = blockIdx.x * 256 + threadIdx.x;  // i = t*2 + k
  if (i >= 8192) return;
  const int e = eidx[i];
  const int pos = offsets[e] + atomicAdd(&fill[e], 1);
  pos_tk[i] = pos;
  tok_of_pos[pos] = i >> 1;
}

__global__ void swiglu_mul(const us* __restrict__ a, const us* __restrict__ b,
                           us* __restrict__ c, int n){
  const int i = (blockIdx.x * 256 + threadIdx.x) * 8;
  if (i >= n) return;
  s16x8 va = *reinterpret_cast<const s16x8*>(a + i);
  s16x8 vb = *reinterpret_cast<const s16x8*>(b + i);
  s16x8 vc;
#pragma unroll
  for (int k = 0; k < 8; ++k) vc[k] = (short)f2b(b2f((us)va[k]) * b2f((us)vb[k]));
  *reinterpret_cast<s16x8*>(c + i) = vc;
}

__global__ void combine_kernel(const float* __restrict__ eo, const float* __restrict__ shr,
                               const int* __restrict__ pos_tk, const float* __restrict__ gates,
                               us* __restrict__ comb){
  const int t = blockIdx.x;
  const int c = threadIdx.x * 4;
  const int p0 = pos_tk[t*2], p1 = pos_tk[t*2+1];
  const float g0 = gates[t*2], g1 = gates[t*2+1];
  f32x4 a = *reinterpret_cast<const f32x4*>(eo + (size_t)p0 * 1024 + c);
  f32x4 b = *reinterpret_cast<const f32x4*>(eo + (size_t)p1 * 1024 + c);
  f32x4 s = *reinterpret_cast<const f32x4*>(shr + (size_t)t * 1024 + c);
  s16x4 o;
#pragma unroll
  for (int k = 0; k < 4; ++k) o[k] = (short)f2b(g0 * a[k] + g1 * b[k] + s[k]);
  *reinterpret_cast<s16x4*>(comb + (size_t)t * 1024 + c) = o;
}

__global__ void store_out(const float* __restrict__ src, void* __restrict__ dst, int n,
                          const int* __restrict__ flag){
  const int i = blockIdx.x * 256 + threadIdx.x;
  if (i >= n) return;
  const float v = src[i];
  if (*flag) ((float*)dst)[i] = v;
  else       ((us*)dst)[i] = f2b(v);
}

// ---------------------------------------------------------------------------
extern "C" void kernel_launch(void* const* d_in, const int* in_sizes, int n_in,
                              void* d_out, int out_size, void* d_ws, size_t ws_size,
                              hipStream_t stream)
{
  const void* x      = d_in[0];
  const void* Wproj  = d_in[1];
  const us*   bproj  = (const us*)d_in[2];   // zeros
  const void* Wg     = d_in[3];
  const void* W1     = d_in[4];
  const us*   b1     = (const us*)d_in[5];   // zeros
  const void* W2     = d_in[6];
  const us*   b2     = (const us*)d_in[7];   // zeros
  const void* sg_w   = d_in[8];
  const us*   sg_b   = (const us*)d_in[9];   // zeros
  const void* su_w   = d_in[10];
  const us*   su_b   = (const us*)d_in[11];  // zeros
  const void* sd_w   = d_in[12];
  const us*   sd_b   = (const us*)d_in[13];  // zeros
  const void* m1_w   = d_in[14];
  const us*   m1_b   = (const us*)d_in[15];  // zeros
  const void* m2_w   = d_in[16];
  const us*   m2_b   = (const us*)d_in[17];  // zeros
  const void* head_w = d_in[18];
  const us*   head_b = (const us*)d_in[19];  // zeros

  char* ws = (char*)d_ws;
  size_t off = 0;
  auto take = [&](size_t bytes) -> char* {
    char* p = ws + off; off += (bytes + 255) & ~(size_t)255; return p;
  };
  us* wprojT = (us*)take(1024ULL*512*2);
  us* w1T    = (us*)take(8ULL*2048*1024*2);
  us* w2T    = (us*)take(8ULL*1024*2048*2);
  us* sgT    = (us*)take(4096ULL*1024*2);
  us* suT    = (us*)take(4096ULL*1024*2);
  us* sdT    = (us*)take(1024ULL*4096*2);
  us* m1T    = (us*)take(2048ULL*1024*2);
  us* m2T    = (us*)take(2048ULL*2048*2);
  us* headT  = (us*)take(128ULL*2048*2);
  us* xb     = (us*)take(4096ULL*512*2);
  us* pbf    = (us*)take(4096ULL*1024*2);
  float* Mrt = (float*)take(512ULL*8*4);
  char* bufA = take(33554432);   // g_silu -> h -> hid2
  char* bufB = take(33554432);   // u      -> eo(fp32)
  char* bufC = take(33554432);   // s_in   -> [combined | hid1]
  float* shrF = (float*)take(4096ULL*1024*4);
  float* houtF = (float*)take(4096ULL*29*4);
  int* ctrl   = (int*)take(256); // counts[8], fill[8], offsets[9], flag @28
  int* eidx   = (int*)take(8192*4);
  float* gbuf = (float*)take(8192*4);
  int* postk  = (int*)take(8192*4);
  int* tokpos = (int*)take(8192*4);
  int* counts  = ctrl;
  int* fill    = ctrl + 8;
  int* offs    = ctrl + 16;
  int* dflag   = ctrl + 28;

  us* comb = (us*)bufC;
  us* hid1 = (us*)(bufC + 8388608);
  us* hid2 = (us*)bufA;

  const dim3 T(256);

  // --- dtype detect ---
  detect_kernel<<<dim3(1), T, 0, stream>>>((const unsigned*)x, dflag);

  // --- routing in full fp32: M = Wproj@Wg, logits = x@M ---
  hipMemsetAsync(ctrl, 0, 64, stream);   // counts + fill (flag untouched)
  compose_router<<<dim3(128), T, 0, stream>>>(Wproj, Wg, Mrt, dflag);
  router2<<<dim3(1024), T, 0, stream>>>(x, Mrt, eidx, gbuf, counts, dflag);
  scan_kernel<<<dim3(1), dim3(64), 0, stream>>>(counts, offs);
  fill_kernel<<<dim3(32), T, 0, stream>>>(eidx, offs, fill, postk, tokpos);

  // --- weight transposes ([R,C] -> bf16 [Cp,R]) ---
  transpose_any<<<dim3(32, 16, 1), T, 0, stream>>>(Wproj, wprojT, 512, 1024, 0, 0, dflag);
  transpose_any<<<dim3(64, 32, 8), T, 0, stream>>>(W1, w1T, 1024, 2048, 1024LL*2048, 2048LL*1024, dflag);
  transpose_any<<<dim3(32, 64, 8), T, 0, stream>>>(W2, w2T, 2048, 1024, 2048LL*1024, 1024LL*2048, dflag);
  transpose_any<<<dim3(128, 32, 1), T, 0, stream>>>(sg_w, sgT, 1024, 4096, 0, 0, dflag);
  transpose_any<<<dim3(128, 32, 1), T, 0, stream>>>(su_w, suT, 1024, 4096, 0, 0, dflag);
  transpose_any<<<dim3(32, 128, 1), T, 0, stream>>>(sd_w, sdT, 4096, 1024, 0, 0, dflag);
  transpose_any<<<dim3(64, 32, 1), T, 0, stream>>>(m1_w, m1T, 1024, 2048, 0, 0, dflag);
  transpose_any<<<dim3(64, 64, 1), T, 0, stream>>>(m2_w, m2T, 2048, 2048, 0, 0, dflag);
  transpose_any<<<dim3(4, 64, 1), T, 0, stream>>>(head_w, headT, 2048, 29, 0, 0, dflag);

  // --- x -> bf16, input projection -> bf16 p ---
  cvt_any_bf<<<dim3(2048), T, 0, stream>>>(x, xb, 4096*512, dflag);
  gemm_plain<true,false><<<dim3(8, 32), T, 0, stream>>>(xb, 512, wprojT, 512, pbf, 1024, bproj, 4096, 1024, 512, 1024);

  // --- shared experts (SwiGLU) ---
  gemm_plain<true,true ><<<dim3(32, 32), T, 0, stream>>>(pbf, 1024, sgT, 1024, bufA, 4096, sg_b, 4096, 4096, 1024, 4096);
  gemm_plain<true,false><<<dim3(32, 32), T, 0, stream>>>(pbf, 1024, suT, 1024, bufB, 4096, su_b, 4096, 4096, 1024, 4096);
  swiglu_mul<<<dim3(8192), T, 0, stream>>>((us*)bufA, (us*)bufB, (us*)bufC, 16777216);
  gemm_plain<false,false><<<dim3(8, 32), T, 0, stream>>>((us*)bufC, 4096, sdT, 4096, shrF, 1024, sd_b, 4096, 1024, 4096, 1024);

  // --- routed experts (top-2 grouped GEMMs over position space) ---
  gemm_group<true,true ><<<dim3(16, 64, 8), T, 0, stream>>>(pbf, 1024, tokpos, offs, w1T, bufA, 2048, b1, 2048, 1024);
  gemm_group<false,false><<<dim3(8, 64, 8), T, 0, stream>>>((us*)bufA, 2048, nullptr, offs, w2T, bufB, 1024, b2, 1024, 2048);
  combine_kernel<<<dim3(4096), T, 0, stream>>>((float*)bufB, shrF, postk, gbuf, comb);

  // --- output MLP + head ---
  gemm_plain<true,true ><<<dim3(16, 32), T, 0, stream>>>(comb, 1024, m1T, 1024, hid1, 2048, m1_b, 4096, 2048, 1024, 2048);
  gemm_plain<true,false><<<dim3(16, 32), T, 0, stream>>>(hid1, 2048, m2T, 2048, hid2, 2048, m2_b, 4096, 2048, 2048, 2048);
  gemm_plain<false,false><<<dim3(1, 32), T, 0, stream>>>(hid2, 2048, headT, 2048, houtF, 29, head_b, 4096, 128, 2048, 29);
  store_out<<<dim3(464), T, 0, stream>>>(houtF, d_out, 4096*29, dflag);

  (void)in_sizes; (void)n_in; (void)out_size; (void)ws_size;
}

// Round 4
// 792.865 us; speedup vs baseline: 1.1987x; 1.1987x over previous
//
#include <hip/hip_runtime.h>
#include <hip/hip_bf16.h>
#include <cstdint>

typedef unsigned short us;
typedef __attribute__((ext_vector_type(4))) float f32x4;
typedef __attribute__((ext_vector_type(8))) short bf16x8;
typedef __attribute__((ext_vector_type(4))) short s16x4;
typedef __attribute__((ext_vector_type(8))) short s16x8;

__device__ __forceinline__ float b2f(us s){
  union { float f; unsigned u; } x; x.u = ((unsigned)s) << 16; return x.f;
}
__device__ __forceinline__ us f2b(float f){
  union { float f; unsigned u; } x; x.f = f;
  unsigned r = x.u + 0x7FFFu + ((x.u >> 16) & 1u);
  return (us)(r >> 16);
}

#define GLDS16(gp, lp) __builtin_amdgcn_global_load_lds( \
    (const __attribute__((address_space(1))) void*)(gp), \
    (__attribute__((address_space(3))) void*)(lp), 16, 0, 0)

// ---------------------------------------------------------------------------
// dtype detector: flag=1 -> inputs fp32 (round-2/3 evidence), 0 -> bf16.
// ---------------------------------------------------------------------------
__global__ void detect_kernel(const unsigned* __restrict__ xw, int* __restrict__ flag){
  __shared__ int cnt;
  if (threadIdx.x == 0) cnt = 0;
  __syncthreads();
  int c = 0;
  for (int i = threadIdx.x; i < 1024; i += 256){
    const unsigned e = (xw[i] >> 7) & 0xFF;
    if (e >= 100 && e <= 140) ++c;
  }
  atomicAdd(&cnt, c);
  __syncthreads();
  if (threadIdx.x == 0) *flag = (cnt < 512) ? 1 : 0;
}

// ---------------------------------------------------------------------------
// Plain GEMM: C[M,N] = A[M,K] @ BT[N,K]^T (+bias)(+silu)(* silu-gate buffer).
// 128x128 tile, BK=32, 4 waves, mfma_f32_16x16x32_bf16, glds width=16.
// MULG: multiply (acc+bias) by bf16 mulg[row*ldc+col] (fused SwiGLU).
// ---------------------------------------------------------------------------
template<bool OUT_BF16, bool SILU, bool MULG>
__global__ __launch_bounds__(256, 2)
void gemm_plain(const us* __restrict__ A, int lda,
                const us* __restrict__ BT, int ldb,
                void* __restrict__ Cout, int ldc,
                const us* __restrict__ bias,
                const us* __restrict__ mulg,
                int M, int N, int K, int Nvalid)
{
  __shared__ us As[128*32];
  __shared__ us Bs[128*32];
  const int bm = blockIdx.y * 128, bn = blockIdx.x * 128;
  const int tid = threadIdx.x, wave = tid >> 6, lane = tid & 63;
  const int llo = lane & 15, lhi = lane >> 4;

  const us* aP[2]; const us* bP[2]; us* lA[2]; us* lB[2];
#pragma unroll
  for (int s = 0; s < 2; ++s){
    const int chunk = s*256 + wave*64 + lane;
    const int r = chunk >> 2, cc = chunk & 3;
    aP[s] = A  + (size_t)(bm + r) * lda + cc*8;
    bP[s] = BT + (size_t)(bn + r) * ldb + cc*8;
    lA[s] = As + (size_t)(s*256 + wave*64) * 8;  // wave-uniform base
    lB[s] = Bs + (size_t)(s*256 + wave*64) * 8;
  }

  f32x4 acc[4][4] = {};
  const int waveM = (wave >> 1) * 64, waveN = (wave & 1) * 64;

  for (int k0 = 0; k0 < K; k0 += 32){
    GLDS16(aP[0] + k0, lA[0]);
    GLDS16(aP[1] + k0, lA[1]);
    GLDS16(bP[0] + k0, lB[0]);
    GLDS16(bP[1] + k0, lB[1]);
    __syncthreads();
    bf16x8 af[4], bv[4];
#pragma unroll
    for (int t = 0; t < 4; ++t){
      af[t] = *reinterpret_cast<const bf16x8*>(As + (waveM + t*16 + llo)*32 + lhi*8);
      bv[t] = *reinterpret_cast<const bf16x8*>(Bs + (waveN + t*16 + llo)*32 + lhi*8);
    }
#pragma unroll
    for (int mt = 0; mt < 4; ++mt)
#pragma unroll
      for (int nt = 0; nt < 4; ++nt)
        acc[mt][nt] = __builtin_amdgcn_mfma_f32_16x16x32_bf16(af[mt], bv[nt], acc[mt][nt], 0, 0, 0);
    __syncthreads();
  }

#pragma unroll
  for (int nt = 0; nt < 4; ++nt){
    const int col = bn + waveN + nt*16 + llo;
    float bb = 0.f;
    if (bias && col < Nvalid) bb = b2f(bias[col]);
#pragma unroll
    for (int mt = 0; mt < 4; ++mt){
      const int row0 = bm + waveM + mt*16 + lhi*4;  // C/D: col=lane&15, row=quad*4+reg
#pragma unroll
      for (int r = 0; r < 4; ++r){
        if (col < Nvalid){
          float v = acc[mt][nt][r] + bb;
          if (SILU) v = v / (1.f + __expf(-v));
          if (MULG) v *= b2f(mulg[(size_t)(row0 + r) * ldc + col]);
          if (OUT_BF16) ((us*)Cout)[(size_t)(row0 + r) * ldc + col] = f2b(v);
          else          ((float*)Cout)[(size_t)(row0 + r) * ldc + col] = v;
        }
      }
    }
  }
}

// ---------------------------------------------------------------------------
// Grouped (MoE) GEMM over position space. blockIdx.z = expert.
// ---------------------------------------------------------------------------
template<bool OUT_BF16, bool SILU>
__global__ __launch_bounds__(256, 2)
void gemm_group(const us* __restrict__ Abase, int lda,
                const int* __restrict__ rowmap,
                const int* __restrict__ offsets,   // [E+1], offsets[E]=8192
                const us* __restrict__ BTbase,     // [E][N][K]
                void* __restrict__ Cout, int ldc,
                const us* __restrict__ biasbase,   // [E][N]
                int N, int K)
{
  const int e   = blockIdx.z;
  const int off = offsets[e];
  const int Te  = offsets[e + 1] - off;
  const int bmL = blockIdx.y * 128;
  if (bmL >= Te) return;

  __shared__ us As[128*32];
  __shared__ us Bs[128*32];
  const us* BT   = BTbase  + (size_t)e * N * K;
  const us* bias = biasbase + (size_t)e * N;
  const int bn = blockIdx.x * 128;
  const int tid = threadIdx.x, wave = tid >> 6, lane = tid & 63;
  const int llo = lane & 15, lhi = lane >> 4;

  const us* aP[2]; const us* bP[2]; us* lA[2]; us* lB[2];
#pragma unroll
  for (int s = 0; s < 2; ++s){
    const int chunk = s*256 + wave*64 + lane;
    const int r = chunk >> 2, cc = chunk & 3;
    int pos = off + bmL + r; if (pos > 8191) pos = 8191; // OOB rows masked on store
    const int arow = rowmap ? rowmap[pos] : pos;
    aP[s] = Abase + (size_t)arow * lda + cc*8;
    bP[s] = BT + (size_t)(bn + r) * K + cc*8;
    lA[s] = As + (size_t)(s*256 + wave*64) * 8;
    lB[s] = Bs + (size_t)(s*256 + wave*64) * 8;
  }

  f32x4 acc[4][4] = {};
  const int waveM = (wave >> 1) * 64, waveN = (wave & 1) * 64;

  for (int k0 = 0; k0 < K; k0 += 32){
    GLDS16(aP[0] + k0, lA[0]);
    GLDS16(aP[1] + k0, lA[1]);
    GLDS16(bP[0] + k0, lB[0]);
    GLDS16(bP[1] + k0, lB[1]);
    __syncthreads();
    bf16x8 af[4], bv[4];
#pragma unroll
    for (int t = 0; t < 4; ++t){
      af[t] = *reinterpret_cast<const bf16x8*>(As + (waveM + t*16 + llo)*32 + lhi*8);
      bv[t] = *reinterpret_cast<const bf16x8*>(Bs + (waveN + t*16 + llo)*32 + lhi*8);
    }
#pragma unroll
    for (int mt = 0; mt < 4; ++mt)
#pragma unroll
      for (int nt = 0; nt < 4; ++nt)
        acc[mt][nt] = __builtin_amdgcn_mfma_f32_16x16x32_bf16(af[mt], bv[nt], acc[mt][nt], 0, 0, 0);
    __syncthreads();
  }

#pragma unroll
  for (int nt = 0; nt < 4; ++nt){
    const int col = bn + waveN + nt*16 + llo;
    const float bb = b2f(bias[col]);
#pragma unroll
    for (int mt = 0; mt < 4; ++mt){
      const int localBase = bmL + waveM + mt*16 + lhi*4;
#pragma unroll
      for (int r = 0; r < 4; ++r){
        const int local = localBase + r;
        if (local < Te){
          float v = acc[mt][nt][r] + bb;
          if (SILU) v = v / (1.f + __expf(-v));
          const size_t row = (size_t)(off + local);
          if (OUT_BF16) ((us*)Cout)[row * ldc + col] = f2b(v);
          else          ((float*)Cout)[row * ldc + col] = v;
        }
      }
    }
  }
}

// ---------------------------------------------------------------------------
// Head GEMM, K-split x8: partials[z][4096][32] fp32. A=[4096,2048] bf16,
// BT=[128,2048] bf16 (rows>=29 zero). blockIdx.z = K-split.
// ---------------------------------------------------------------------------
__global__ __launch_bounds__(256, 2)
void gemm_head(const us* __restrict__ A, const us* __restrict__ BT,
               float* __restrict__ Cpart)
{
  __shared__ us As[128*32];
  __shared__ us Bs[128*32];
  const int bm = blockIdx.y * 128;
  const int koff = blockIdx.z * 256;
  const int tid = threadIdx.x, wave = tid >> 6, lane = tid & 63;
  const int llo = lane & 15, lhi = lane >> 4;

  const us* aP[2]; const us* bP[2]; us* lA[2]; us* lB[2];
#pragma unroll
  for (int s = 0; s < 2; ++s){
    const int chunk = s*256 + wave*64 + lane;
    const int r = chunk >> 2, cc = chunk & 3;
    aP[s] = A  + (size_t)(bm + r) * 2048 + koff + cc*8;
    bP[s] = BT + (size_t)r * 2048 + koff + cc*8;
    lA[s] = As + (size_t)(s*256 + wave*64) * 8;
    lB[s] = Bs + (size_t)(s*256 + wave*64) * 8;
  }

  f32x4 acc[4][4] = {};
  const int waveM = (wave >> 1) * 64, waveN = (wave & 1) * 64;

  for (int k0 = 0; k0 < 256; k0 += 32){
    GLDS16(aP[0] + k0, lA[0]);
    GLDS16(aP[1] + k0, lA[1]);
    GLDS16(bP[0] + k0, lB[0]);
    GLDS16(bP[1] + k0, lB[1]);
    __syncthreads();
    bf16x8 af[4], bv[4];
#pragma unroll
    for (int t = 0; t < 4; ++t){
      af[t] = *reinterpret_cast<const bf16x8*>(As + (waveM + t*16 + llo)*32 + lhi*8);
      bv[t] = *reinterpret_cast<const bf16x8*>(Bs + (waveN + t*16 + llo)*32 + lhi*8);
    }
#pragma unroll
    for (int mt = 0; mt < 4; ++mt)
#pragma unroll
      for (int nt = 0; nt < 4; ++nt)
        acc[mt][nt] = __builtin_amdgcn_mfma_f32_16x16x32_bf16(af[mt], bv[nt], acc[mt][nt], 0, 0, 0);
    __syncthreads();
  }

  float* out = Cpart + (size_t)blockIdx.z * 4096 * 32;
#pragma unroll
  for (int nt = 0; nt < 4; ++nt){
    const int col = waveN + nt*16 + llo;
    if (col >= 29) continue;
#pragma unroll
    for (int mt = 0; mt < 4; ++mt){
      const int row0 = bm + waveM + mt*16 + lhi*4;
#pragma unroll
      for (int r = 0; r < 4; ++r)
        out[(size_t)(row0 + r) * 32 + col] = acc[mt][nt][r];
    }
  }
}

// sum 8 partials + bias, store per flag dtype
__global__ void reduce_head(const float* __restrict__ part, const us* __restrict__ bias,
                            void* __restrict__ dst, const int* __restrict__ flag){
  const int i = blockIdx.x * 256 + threadIdx.x;
  if (i >= 4096*29) return;
  const int t = i / 29, c = i - t * 29;
  float s = b2f(bias[c]);
#pragma unroll
  for (int z = 0; z < 8; ++z) s += part[((size_t)z * 4096 + t) * 32 + c];
  if (*flag) ((float*)dst)[i] = s;
  else       ((us*)dst)[i] = f2b(s);
}

// ---------------------------------------------------------------------------
// [R,C] -> bf16 [Cp,R] transpose; src fp32 (flag=1) or bf16 (flag=0).
// ---------------------------------------------------------------------------
__global__ void transpose_any(const void* __restrict__ src_, us* __restrict__ dst,
                              int R, int C, long long smat, long long dmat,
                              const int* __restrict__ flag)
{
  const int f32 = *flag;
  dst += (size_t)blockIdx.z * dmat;
  __shared__ us tile[32][33];
  const int c0 = blockIdx.x * 32, r0 = blockIdx.y * 32;
  const int tx = threadIdx.x & 31, ty = threadIdx.x >> 5;  // 32x8
#pragma unroll
  for (int i = 0; i < 4; ++i){
    const int r = r0 + ty + i*8, c = c0 + tx;
    const size_t idx = (size_t)blockIdx.z * smat + (size_t)r * C + c;
    us v = 0;
    if (c < C){
      if (f32) v = f2b(((const float*)src_)[idx]);
      else     v = ((const us*)src_)[idx];
    }
    tile[ty + i*8][tx] = v;
  }
  __syncthreads();
#pragma unroll
  for (int i = 0; i < 4; ++i){
    const int dr = c0 + ty + i*8;
    dst[(size_t)dr * R + r0 + tx] = tile[tx][ty + i*8];
  }
}

__global__ void cvt_any_bf(const void* __restrict__ src, us* __restrict__ dst, int n,
                           const int* __restrict__ flag){
  const int i = (blockIdx.x * 256 + threadIdx.x) * 4;
  if (i >= n) return;
  s16x4 o;
  if (*flag){
    f32x4 v = *reinterpret_cast<const f32x4*>((const float*)src + i);
#pragma unroll
    for (int k = 0; k < 4; ++k) o[k] = (short)f2b(v[k]);
  } else {
    o = *reinterpret_cast<const s16x4*>((const us*)src + i);
  }
  *reinterpret_cast<s16x4*>(dst + i) = o;
}

// ---------------------------------------------------------------------------
// Router fidelity path (all fp32): M = Wproj @ Wg [512,8]; one wave per row.
// ---------------------------------------------------------------------------
__global__ void compose_router(const void* __restrict__ Wproj, const void* __restrict__ Wg,
                               float* __restrict__ M, const int* __restrict__ flag)
{
  const int f32 = *flag;
  const int wave = threadIdx.x >> 6, lane = threadIdx.x & 63;
  const int d = blockIdx.x * 4 + wave;
  float acc[8] = {0,0,0,0,0,0,0,0};
  for (int n = lane; n < 1024; n += 64){
    float wp;
    if (f32) wp = ((const float*)Wproj)[(size_t)d * 1024 + n];
    else     wp = b2f(((const us*)Wproj)[(size_t)d * 1024 + n]);
    if (f32){
      const float* wg = (const float*)Wg + (size_t)n * 8;
#pragma unroll
      for (int e = 0; e < 8; ++e) acc[e] += wp * wg[e];
    } else {
      const s16x8 wg = *reinterpret_cast<const s16x8*>((const us*)Wg + (size_t)n * 8);
#pragma unroll
      for (int e = 0; e < 8; ++e) acc[e] += wp * b2f((us)wg[e]);
    }
  }
#pragma unroll
  for (int e = 0; e < 8; ++e){
    float v = acc[e];
    for (int off = 32; off > 0; off >>= 1) v += __shfl_down(v, off);
    if (lane == 0) M[(size_t)d * 8 + e] = v;
  }
}

// logits[t] = x[t] @ M (fp32); top-2 + sigmoid gates. NO atomics (round-4 fix:
// the 8192 contended atomicAdds on counts[8] serialized at ~12ns each = 100us).
__global__ void router2(const void* __restrict__ x, const float* __restrict__ M,
                        int* __restrict__ eidx, float* __restrict__ gates,
                        const int* __restrict__ flag)
{
  const int f32 = *flag;
  const int wave = threadIdx.x >> 6, lane = threadIdx.x & 63;
  const int t = blockIdx.x * 4 + wave;
  float l[8] = {0,0,0,0,0,0,0,0};
  for (int d = lane; d < 512; d += 64){
    float xv;
    if (f32) xv = ((const float*)x)[(size_t)t * 512 + d];
    else     xv = b2f(((const us*)x)[(size_t)t * 512 + d]);
    const float* mr = M + (size_t)d * 8;
#pragma unroll
    for (int e = 0; e < 8; ++e) l[e] += xv * mr[e];
  }
#pragma unroll
  for (int e = 0; e < 8; ++e){
    float v = l[e];
    for (int off = 32; off > 0; off >>= 1) v += __shfl_down(v, off);
    l[e] = v;
  }
  if (lane == 0){
    int e0 = 0; float v0 = l[0];
#pragma unroll
    for (int e = 1; e < 8; ++e) if (l[e] > v0){ v0 = l[e]; e0 = e; }
    int e1 = (e0 == 0) ? 1 : 0; float v1 = l[e1];
#pragma unroll
    for (int e = 0; e < 8; ++e) if (e != e0 && l[e] > v1){ v1 = l[e]; e1 = e; }
    const float g1 = 1.f / (1.f + __expf(v0 - v1));
    eidx[t*2] = e0;  eidx[t*2+1] = e1;
    gates[t*2] = 1.f - g1; gates[t*2+1] = g1;
  }
}

// LDS histogram of eidx -> counts. 32 blocks x 256; 8 global atomics/block.
__global__ void hist_kernel(const int* __restrict__ eidx, int* __restrict__ counts){
  __shared__ int lh[8];
  if (threadIdx.x < 8) lh[threadIdx.x] = 0;
  __syncthreads();
  const int i = blockIdx.x * 256 + threadIdx.x;
  atomicAdd(&lh[eidx[i]], 1);
  __syncthreads();
  if (threadIdx.x < 8) atomicAdd(&counts[threadIdx.x], lh[threadIdx.x]);
}

__global__ void scan_kernel(const int* __restrict__ counts, int* __restrict__ offsets){
  if (threadIdx.x == 0){
    int s = 0;
    for (int e = 0; e < 8; ++e){ offsets[e] = s; s += counts[e]; }
    offsets[8] = s;
  }
}

// per-block LDS rank + one 8-atomic base claim per block (256 global atomics).
__global__ void fill_kernel(const int* __restrict__ eidx, const int* __restrict__ offsets,
                            int* __restrict__ fillg, int* __restrict__ pos_tk,
                            int* __restrict__ tok_of_pos){
  __shared__ int lh[8];
  __shared__ int lbase[8];
  if (threadIdx.x < 8) lh[threadIdx.x] = 0;
  __syncthreads();
  const int i = blockIdx.x * 256 + threadIdx.x;  // i = t*2 + k
  const int e = eidx[i];
  const int r = atomicAdd(&lh[e], 1);
  __syncthreads();
  if (threadIdx.x < 8) lbase[threadIdx.x] = atomicAdd(&fillg[threadIdx.x], lh[threadIdx.x]);
  __syncthreads();
  const int pos = offsets[e] + lbase[e] + r;
  pos_tk[i] = pos;
  tok_of_pos[pos] = i >> 1;
}

__global__ void combine_kernel(const float* __restrict__ eo, const float* __restrict__ shr,
                               const int* __restrict__ pos_tk, const float* __restrict__ gates,
                               us* __restrict__ comb){
  const int t = blockIdx.x;
  const int c = threadIdx.x * 4;
  const int p0 = pos_tk[t*2], p1 = pos_tk[t*2+1];
  const float g0 = gates[t*2], g1 = gates[t*2+1];
  f32x4 a = *reinterpret_cast<const f32x4*>(eo + (size_t)p0 * 1024 + c);
  f32x4 b = *reinterpret_cast<const f32x4*>(eo + (size_t)p1 * 1024 + c);
  f32x4 s = *reinterpret_cast<const f32x4*>(shr + (size_t)t * 1024 + c);
  s16x4 o;
#pragma unroll
  for (int k = 0; k < 4; ++k) o[k] = (short)f2b(g0 * a[k] + g1 * b[k] + s[k]);
  *reinterpret_cast<s16x4*>(comb + (size_t)t * 1024 + c) = o;
}

// ---------------------------------------------------------------------------
extern "C" void kernel_launch(void* const* d_in, const int* in_sizes, int n_in,
                              void* d_out, int out_size, void* d_ws, size_t ws_size,
                              hipStream_t stream)
{
  const void* x      = d_in[0];
  const void* Wproj  = d_in[1];
  const us*   bproj  = (const us*)d_in[2];   // zeros
  const void* Wg     = d_in[3];
  const void* W1     = d_in[4];
  const us*   b1     = (const us*)d_in[5];   // zeros
  const void* W2     = d_in[6];
  const us*   b2     = (const us*)d_in[7];   // zeros
  const void* sg_w   = d_in[8];
  const us*   sg_b   = (const us*)d_in[9];   // zeros
  const void* su_w   = d_in[10];
  const us*   su_b   = (const us*)d_in[11];  // zeros
  const void* sd_w   = d_in[12];
  const us*   sd_b   = (const us*)d_in[13];  // zeros
  const void* m1_w   = d_in[14];
  const us*   m1_b   = (const us*)d_in[15];  // zeros
  const void* m2_w   = d_in[16];
  const us*   m2_b   = (const us*)d_in[17];  // zeros
  const void* head_w = d_in[18];
  const us*   head_b = (const us*)d_in[19];  // zeros

  char* ws = (char*)d_ws;
  size_t off = 0;
  auto take = [&](size_t bytes) -> char* {
    char* p = ws + off; off += (bytes + 255) & ~(size_t)255; return p;
  };
  us* wprojT = (us*)take(1024ULL*512*2);
  us* w1T    = (us*)take(8ULL*2048*1024*2);
  us* w2T    = (us*)take(8ULL*1024*2048*2);
  us* sgT    = (us*)take(4096ULL*1024*2);
  us* suT    = (us*)take(4096ULL*1024*2);
  us* sdT    = (us*)take(1024ULL*4096*2);
  us* m1T    = (us*)take(2048ULL*1024*2);
  us* m2T    = (us*)take(2048ULL*2048*2);
  us* headT  = (us*)take(128ULL*2048*2);
  us* xb     = (us*)take(4096ULL*512*2);
  us* pbf    = (us*)take(4096ULL*1024*2);
  float* Mrt = (float*)take(512ULL*8*4);
  char* bufA = take(33554432);   // g_silu -> h -> hid2
  char* bufB = take(33554432);   // u-unused -> eo(fp32)
  char* bufC = take(33554432);   // s_in -> [combined | hid1]
  float* shrF  = (float*)take(4096ULL*1024*4);
  float* houtP = (float*)take(8ULL*4096*32*4);
  int* ctrl   = (int*)take(256); // counts[8], fill[8], offsets[9], flag @28
  int* eidx   = (int*)take(8192*4);
  float* gbuf = (float*)take(8192*4);
  int* postk  = (int*)take(8192*4);
  int* tokpos = (int*)take(8192*4);
  int* counts  = ctrl;
  int* fill    = ctrl + 8;
  int* offs    = ctrl + 16;
  int* dflag   = ctrl + 28;

  us* comb = (us*)bufC;
  us* hid1 = (us*)(bufC + 8388608);
  us* hid2 = (us*)bufA;

  const dim3 T(256);
  const us* nomul = nullptr;

  // --- dtype detect ---
  detect_kernel<<<dim3(1), T, 0, stream>>>((const unsigned*)x, dflag);

  // --- routing in full fp32: M = Wproj@Wg, logits = x@M ---
  hipMemsetAsync(ctrl, 0, 64, stream);   // counts + fill (flag untouched)
  compose_router<<<dim3(128), T, 0, stream>>>(Wproj, Wg, Mrt, dflag);
  router2<<<dim3(1024), T, 0, stream>>>(x, Mrt, eidx, gbuf, dflag);
  hist_kernel<<<dim3(32), T, 0, stream>>>(eidx, counts);
  scan_kernel<<<dim3(1), dim3(64), 0, stream>>>(counts, offs);
  fill_kernel<<<dim3(32), T, 0, stream>>>(eidx, offs, fill, postk, tokpos);

  // --- weight transposes ([R,C] -> bf16 [Cp,R]) ---
  transpose_any<<<dim3(32, 16, 1), T, 0, stream>>>(Wproj, wprojT, 512, 1024, 0, 0, dflag);
  transpose_any<<<dim3(64, 32, 8), T, 0, stream>>>(W1, w1T, 1024, 2048, 1024LL*2048, 2048LL*1024, dflag);
  transpose_any<<<dim3(32, 64, 8), T, 0, stream>>>(W2, w2T, 2048, 1024, 2048LL*1024, 1024LL*2048, dflag);
  transpose_any<<<dim3(128, 32, 1), T, 0, stream>>>(sg_w, sgT, 1024, 4096, 0, 0, dflag);
  transpose_any<<<dim3(128, 32, 1), T, 0, stream>>>(su_w, suT, 1024, 4096, 0, 0, dflag);
  transpose_any<<<dim3(32, 128, 1), T, 0, stream>>>(sd_w, sdT, 4096, 1024, 0, 0, dflag);
  transpose_any<<<dim3(64, 32, 1), T, 0, stream>>>(m1_w, m1T, 1024, 2048, 0, 0, dflag);
  transpose_any<<<dim3(64, 64, 1), T, 0, stream>>>(m2_w, m2T, 2048, 2048, 0, 0, dflag);
  transpose_any<<<dim3(4, 64, 1), T, 0, stream>>>(head_w, headT, 2048, 29, 0, 0, dflag);

  // --- x -> bf16, input projection -> bf16 p ---
  cvt_any_bf<<<dim3(2048), T, 0, stream>>>(x, xb, 4096*512, dflag);
  gemm_plain<true,false,false><<<dim3(8, 32), T, 0, stream>>>(xb, 512, wprojT, 512, pbf, 1024, bproj, nomul, 4096, 1024, 512, 1024);

  // --- shared experts (SwiGLU; multiply fused into su epilogue) ---
  gemm_plain<true,true ,false><<<dim3(32, 32), T, 0, stream>>>(pbf, 1024, sgT, 1024, bufA, 4096, sg_b, nomul, 4096, 4096, 1024, 4096);
  gemm_plain<true,false,true ><<<dim3(32, 32), T, 0, stream>>>(pbf, 1024, suT, 1024, bufC, 4096, su_b, (const us*)bufA, 4096, 4096, 1024, 4096);
  gemm_plain<false,false,false><<<dim3(8, 32), T, 0, stream>>>((us*)bufC, 4096, sdT, 4096, shrF, 1024, sd_b, nomul, 4096, 1024, 4096, 1024);

  // --- routed experts (top-2 grouped GEMMs over position space) ---
  gemm_group<true,true ><<<dim3(16, 64, 8), T, 0, stream>>>(pbf, 1024, tokpos, offs, w1T, bufA, 2048, b1, 2048, 1024);
  gemm_group<false,false><<<dim3(8, 64, 8), T, 0, stream>>>((us*)bufA, 2048, nullptr, offs, w2T, bufB, 1024, b2, 1024, 2048);
  combine_kernel<<<dim3(4096), T, 0, stream>>>((float*)bufB, shrF, postk, gbuf, comb);

  // --- output MLP + head (head K-split x8 + reduce) ---
  gemm_plain<true,true ,false><<<dim3(16, 32), T, 0, stream>>>(comb, 1024, m1T, 1024, hid1, 2048, m1_b, nomul, 4096, 2048, 1024, 2048);
  gemm_plain<true,false,false><<<dim3(16, 32), T, 0, stream>>>(hid1, 2048, m2T, 2048, hid2, 2048, m2_b, nomul, 4096, 2048, 2048, 2048);
  gemm_head<<<dim3(1, 32, 8), T, 0, stream>>>(hid2, headT, houtP);
  reduce_head<<<dim3(464), T, 0, stream>>>(houtP, head_b, d_out, dflag);

  (void)in_sizes; (void)n_in; (void)out_size; (void)ws_size;
}

// Round 5
// 759.563 us; speedup vs baseline: 1.2513x; 1.0438x over previous
//
#include <hip/hip_runtime.h>
#include <hip/hip_bf16.h>
#include <cstdint>

typedef unsigned short us;
typedef __attribute__((ext_vector_type(4))) float f32x4;
typedef __attribute__((ext_vector_type(8))) short bf16x8;
typedef __attribute__((ext_vector_type(4))) short s16x4;
typedef __attribute__((ext_vector_type(8))) short s16x8;

__device__ __forceinline__ float b2f(us s){
  union { float f; unsigned u; } x; x.u = ((unsigned)s) << 16; return x.f;
}
__device__ __forceinline__ us f2b(float f){
  union { float f; unsigned u; } x; x.f = f;
  unsigned r = x.u + 0x7FFFu + ((x.u >> 16) & 1u);
  return (us)(r >> 16);
}

#define GLDS16(gp, lp) __builtin_amdgcn_global_load_lds( \
    (const __attribute__((address_space(1))) void*)(gp), \
    (__attribute__((address_space(3))) void*)(lp), 16, 0, 0)

// ---------------------------------------------------------------------------
// XCD-aware swizzle (round-5): workgroup->XCD is lin%8 round-robin; remap so
// each XCD owns a compact 8(bm) x gx/2(bn) tile rectangle -> per-XCD L2
// footprint ~6-10MB instead of the whole A+B (round-4 FETCH=135MB evidence).
// Valid for gy==32, gx even. Identity otherwise.
// ---------------------------------------------------------------------------
__device__ __forceinline__ void xcd_swizzle(int& bm, int& bn){
  const int gx = gridDim.x;
  if (gridDim.y == 32 && (gx & 1) == 0 && gx >= 8){
    const int lin = blockIdx.y * gx + blockIdx.x;
    const int xcd = lin & 7, r = lin >> 3;
    bm = (xcd & 3) * 8 + (r & 7);
    bn = (xcd >> 2) * (gx >> 1) + (r >> 3);
  } else { bm = blockIdx.y; bn = blockIdx.x; }
}

// ---------------------------------------------------------------------------
// dtype detector: flag=1 -> inputs fp32 (round-2/3 evidence), 0 -> bf16.
// ---------------------------------------------------------------------------
__global__ void detect_kernel(const unsigned* __restrict__ xw, int* __restrict__ flag){
  __shared__ int cnt;
  if (threadIdx.x == 0) cnt = 0;
  __syncthreads();
  int c = 0;
  for (int i = threadIdx.x; i < 1024; i += 256){
    const unsigned e = (xw[i] >> 7) & 0xFF;
    if (e >= 100 && e <= 140) ++c;
  }
  atomicAdd(&cnt, c);
  __syncthreads();
  if (threadIdx.x == 0) *flag = (cnt < 512) ? 1 : 0;
}

// ---------------------------------------------------------------------------
// Plain GEMM: C[M,N] = A[M,K] @ BT[N,K]^T (+bias)(+silu). 128x128 tile, BK=32,
// 4 waves, mfma_f32_16x16x32_bf16, glds width=16, XCD swizzle.
// ---------------------------------------------------------------------------
template<bool OUT_BF16, bool SILU>
__global__ __launch_bounds__(256, 2)
void gemm_plain(const us* __restrict__ A, int lda,
                const us* __restrict__ BT, int ldb,
                void* __restrict__ Cout, int ldc,
                const us* __restrict__ bias,
                int M, int N, int K, int Nvalid)
{
  __shared__ us As[128*32];
  __shared__ us Bs[128*32];
  int bmi, bni; xcd_swizzle(bmi, bni);
  const int bm = bmi * 128, bn = bni * 128;
  const int tid = threadIdx.x, wave = tid >> 6, lane = tid & 63;
  const int llo = lane & 15, lhi = lane >> 4;

  const us* aP[2]; const us* bP[2]; us* lA[2]; us* lB[2];
#pragma unroll
  for (int s = 0; s < 2; ++s){
    const int chunk = s*256 + wave*64 + lane;
    const int r = chunk >> 2, cc = chunk & 3;
    aP[s] = A  + (size_t)(bm + r) * lda + cc*8;
    bP[s] = BT + (size_t)(bn + r) * ldb + cc*8;
    lA[s] = As + (size_t)(s*256 + wave*64) * 8;  // wave-uniform base
    lB[s] = Bs + (size_t)(s*256 + wave*64) * 8;
  }

  f32x4 acc[4][4] = {};
  const int waveM = (wave >> 1) * 64, waveN = (wave & 1) * 64;

  for (int k0 = 0; k0 < K; k0 += 32){
    GLDS16(aP[0] + k0, lA[0]);
    GLDS16(aP[1] + k0, lA[1]);
    GLDS16(bP[0] + k0, lB[0]);
    GLDS16(bP[1] + k0, lB[1]);
    __syncthreads();
    bf16x8 af[4], bv[4];
#pragma unroll
    for (int t = 0; t < 4; ++t){
      af[t] = *reinterpret_cast<const bf16x8*>(As + (waveM + t*16 + llo)*32 + lhi*8);
      bv[t] = *reinterpret_cast<const bf16x8*>(Bs + (waveN + t*16 + llo)*32 + lhi*8);
    }
#pragma unroll
    for (int mt = 0; mt < 4; ++mt)
#pragma unroll
      for (int nt = 0; nt < 4; ++nt)
        acc[mt][nt] = __builtin_amdgcn_mfma_f32_16x16x32_bf16(af[mt], bv[nt], acc[mt][nt], 0, 0, 0);
    __syncthreads();
  }

#pragma unroll
  for (int nt = 0; nt < 4; ++nt){
    const int col = bn + waveN + nt*16 + llo;
    float bb = 0.f;
    if (bias && col < Nvalid) bb = b2f(bias[col]);
#pragma unroll
    for (int mt = 0; mt < 4; ++mt){
      const int row0 = bm + waveM + mt*16 + lhi*4;  // C/D: col=lane&15, row=quad*4+reg
#pragma unroll
      for (int r = 0; r < 4; ++r){
        if (col < Nvalid){
          float v = acc[mt][nt][r] + bb;
          if (SILU) v = v / (1.f + __expf(-v));
          if (OUT_BF16) ((us*)Cout)[(size_t)(row0 + r) * ldc + col] = f2b(v);
          else          ((float*)Cout)[(size_t)(row0 + r) * ldc + col] = v;
        }
      }
    }
  }
}

// ---------------------------------------------------------------------------
// Fused shared-expert SwiGLU up-projections: one A-pass, two B matrices.
// s_in = silu(p@sg+sg_b) * (p@su+su_b). M=N=4096, K=1024 hardcoded.
// ---------------------------------------------------------------------------
__global__ __launch_bounds__(256, 2)
void gemm_sgsu(const us* __restrict__ A, const us* __restrict__ B1T,
               const us* __restrict__ B2T, const us* __restrict__ bias1,
               const us* __restrict__ bias2, us* __restrict__ Cout)
{
  __shared__ us As[128*32];
  __shared__ us B1s[128*32];
  __shared__ us B2s[128*32];
  int bmi, bni; xcd_swizzle(bmi, bni);
  const int bm = bmi * 128, bn = bni * 128;
  const int tid = threadIdx.x, wave = tid >> 6, lane = tid & 63;
  const int llo = lane & 15, lhi = lane >> 4;

  const us* aP[2]; const us* b1P[2]; const us* b2P[2];
  us* lA[2]; us* lB1[2]; us* lB2[2];
#pragma unroll
  for (int s = 0; s < 2; ++s){
    const int chunk = s*256 + wave*64 + lane;
    const int r = chunk >> 2, cc = chunk & 3;
    aP[s]  = A   + (size_t)(bm + r) * 1024 + cc*8;
    b1P[s] = B1T + (size_t)(bn + r) * 1024 + cc*8;
    b2P[s] = B2T + (size_t)(bn + r) * 1024 + cc*8;
    lA[s]  = As  + (size_t)(s*256 + wave*64) * 8;
    lB1[s] = B1s + (size_t)(s*256 + wave*64) * 8;
    lB2[s] = B2s + (size_t)(s*256 + wave*64) * 8;
  }

  f32x4 acc1[4][4] = {};
  f32x4 acc2[4][4] = {};
  const int waveM = (wave >> 1) * 64, waveN = (wave & 1) * 64;

  for (int k0 = 0; k0 < 1024; k0 += 32){
    GLDS16(aP[0] + k0, lA[0]);
    GLDS16(aP[1] + k0, lA[1]);
    GLDS16(b1P[0] + k0, lB1[0]);
    GLDS16(b1P[1] + k0, lB1[1]);
    GLDS16(b2P[0] + k0, lB2[0]);
    GLDS16(b2P[1] + k0, lB2[1]);
    __syncthreads();
    bf16x8 af[4], b1v[4], b2v[4];
#pragma unroll
    for (int t = 0; t < 4; ++t){
      af[t]  = *reinterpret_cast<const bf16x8*>(As  + (waveM + t*16 + llo)*32 + lhi*8);
      b1v[t] = *reinterpret_cast<const bf16x8*>(B1s + (waveN + t*16 + llo)*32 + lhi*8);
      b2v[t] = *reinterpret_cast<const bf16x8*>(B2s + (waveN + t*16 + llo)*32 + lhi*8);
    }
#pragma unroll
    for (int mt = 0; mt < 4; ++mt)
#pragma unroll
      for (int nt = 0; nt < 4; ++nt){
        acc1[mt][nt] = __builtin_amdgcn_mfma_f32_16x16x32_bf16(af[mt], b1v[nt], acc1[mt][nt], 0, 0, 0);
        acc2[mt][nt] = __builtin_amdgcn_mfma_f32_16x16x32_bf16(af[mt], b2v[nt], acc2[mt][nt], 0, 0, 0);
      }
    __syncthreads();
  }

#pragma unroll
  for (int nt = 0; nt < 4; ++nt){
    const int col = bn + waveN + nt*16 + llo;
    const float bb1 = b2f(bias1[col]);
    const float bb2 = b2f(bias2[col]);
#pragma unroll
    for (int mt = 0; mt < 4; ++mt){
      const int row0 = bm + waveM + mt*16 + lhi*4;
#pragma unroll
      for (int r = 0; r < 4; ++r){
        const float g = acc1[mt][nt][r] + bb1;
        const float v = (g / (1.f + __expf(-g))) * (acc2[mt][nt][r] + bb2);
        Cout[(size_t)(row0 + r) * 4096 + col] = f2b(v);
      }
    }
  }
}

// ---------------------------------------------------------------------------
// Grouped (MoE) GEMM over position space. blockIdx.z = expert.
// ---------------------------------------------------------------------------
template<bool OUT_BF16, bool SILU>
__global__ __launch_bounds__(256, 2)
void gemm_group(const us* __restrict__ Abase, int lda,
                const int* __restrict__ rowmap,
                const int* __restrict__ offsets,   // [E+1], offsets[E]=8192
                const us* __restrict__ BTbase,     // [E][N][K]
                void* __restrict__ Cout, int ldc,
                const us* __restrict__ biasbase,   // [E][N]
                int N, int K)
{
  const int e   = blockIdx.z;
  const int off = offsets[e];
  const int Te  = offsets[e + 1] - off;
  const int bmL = blockIdx.y * 128;
  if (bmL >= Te) return;

  __shared__ us As[128*32];
  __shared__ us Bs[128*32];
  const us* BT   = BTbase  + (size_t)e * N * K;
  const us* bias = biasbase + (size_t)e * N;
  const int bn = blockIdx.x * 128;
  const int tid = threadIdx.x, wave = tid >> 6, lane = tid & 63;
  const int llo = lane & 15, lhi = lane >> 4;

  const us* aP[2]; const us* bP[2]; us* lA[2]; us* lB[2];
#pragma unroll
  for (int s = 0; s < 2; ++s){
    const int chunk = s*256 + wave*64 + lane;
    const int r = chunk >> 2, cc = chunk & 3;
    int pos = off + bmL + r; if (pos > 8191) pos = 8191; // OOB rows masked on store
    const int arow = rowmap ? rowmap[pos] : pos;
    aP[s] = Abase + (size_t)arow * lda + cc*8;
    bP[s] = BT + (size_t)(bn + r) * K + cc*8;
    lA[s] = As + (size_t)(s*256 + wave*64) * 8;
    lB[s] = Bs + (size_t)(s*256 + wave*64) * 8;
  }

  f32x4 acc[4][4] = {};
  const int waveM = (wave >> 1) * 64, waveN = (wave & 1) * 64;

  for (int k0 = 0; k0 < K; k0 += 32){
    GLDS16(aP[0] + k0, lA[0]);
    GLDS16(aP[1] + k0, lA[1]);
    GLDS16(bP[0] + k0, lB[0]);
    GLDS16(bP[1] + k0, lB[1]);
    __syncthreads();
    bf16x8 af[4], bv[4];
#pragma unroll
    for (int t = 0; t < 4; ++t){
      af[t] = *reinterpret_cast<const bf16x8*>(As + (waveM + t*16 + llo)*32 + lhi*8);
      bv[t] = *reinterpret_cast<const bf16x8*>(Bs + (waveN + t*16 + llo)*32 + lhi*8);
    }
#pragma unroll
    for (int mt = 0; mt < 4; ++mt)
#pragma unroll
      for (int nt = 0; nt < 4; ++nt)
        acc[mt][nt] = __builtin_amdgcn_mfma_f32_16x16x32_bf16(af[mt], bv[nt], acc[mt][nt], 0, 0, 0);
    __syncthreads();
  }

#pragma unroll
  for (int nt = 0; nt < 4; ++nt){
    const int col = bn + waveN + nt*16 + llo;
    const float bb = b2f(bias[col]);
#pragma unroll
    for (int mt = 0; mt < 4; ++mt){
      const int localBase = bmL + waveM + mt*16 + lhi*4;
#pragma unroll
      for (int r = 0; r < 4; ++r){
        const int local = localBase + r;
        if (local < Te){
          float v = acc[mt][nt][r] + bb;
          if (SILU) v = v / (1.f + __expf(-v));
          const size_t row = (size_t)(off + local);
          if (OUT_BF16) ((us*)Cout)[row * ldc + col] = f2b(v);
          else          ((float*)Cout)[row * ldc + col] = v;
        }
      }
    }
  }
}

// ---------------------------------------------------------------------------
// Head GEMM, K-split x8: partials[z][4096][32] fp32.
// ---------------------------------------------------------------------------
__global__ __launch_bounds__(256, 2)
void gemm_head(const us* __restrict__ A, const us* __restrict__ BT,
               float* __restrict__ Cpart)
{
  __shared__ us As[128*32];
  __shared__ us Bs[128*32];
  const int bm = blockIdx.y * 128;
  const int koff = blockIdx.z * 256;
  const int tid = threadIdx.x, wave = tid >> 6, lane = tid & 63;
  const int llo = lane & 15, lhi = lane >> 4;

  const us* aP[2]; const us* bP[2]; us* lA[2]; us* lB[2];
#pragma unroll
  for (int s = 0; s < 2; ++s){
    const int chunk = s*256 + wave*64 + lane;
    const int r = chunk >> 2, cc = chunk & 3;
    aP[s] = A  + (size_t)(bm + r) * 2048 + koff + cc*8;
    bP[s] = BT + (size_t)r * 2048 + koff + cc*8;
    lA[s] = As + (size_t)(s*256 + wave*64) * 8;
    lB[s] = Bs + (size_t)(s*256 + wave*64) * 8;
  }

  f32x4 acc[4][4] = {};
  const int waveM = (wave >> 1) * 64, waveN = (wave & 1) * 64;

  for (int k0 = 0; k0 < 256; k0 += 32){
    GLDS16(aP[0] + k0, lA[0]);
    GLDS16(aP[1] + k0, lA[1]);
    GLDS16(bP[0] + k0, lB[0]);
    GLDS16(bP[1] + k0, lB[1]);
    __syncthreads();
    bf16x8 af[4], bv[4];
#pragma unroll
    for (int t = 0; t < 4; ++t){
      af[t] = *reinterpret_cast<const bf16x8*>(As + (waveM + t*16 + llo)*32 + lhi*8);
      bv[t] = *reinterpret_cast<const bf16x8*>(Bs + (waveN + t*16 + llo)*32 + lhi*8);
    }
#pragma unroll
    for (int mt = 0; mt < 4; ++mt)
#pragma unroll
      for (int nt = 0; nt < 4; ++nt)
        acc[mt][nt] = __builtin_amdgcn_mfma_f32_16x16x32_bf16(af[mt], bv[nt], acc[mt][nt], 0, 0, 0);
    __syncthreads();
  }

  float* out = Cpart + (size_t)blockIdx.z * 4096 * 32;
#pragma unroll
  for (int nt = 0; nt < 4; ++nt){
    const int col = waveN + nt*16 + llo;
    if (col >= 29) continue;
#pragma unroll
    for (int mt = 0; mt < 4; ++mt){
      const int row0 = bm + waveM + mt*16 + lhi*4;
#pragma unroll
      for (int r = 0; r < 4; ++r)
        out[(size_t)(row0 + r) * 32 + col] = acc[mt][nt][r];
    }
  }
}

__global__ void reduce_head(const float* __restrict__ part, const us* __restrict__ bias,
                            void* __restrict__ dst, const int* __restrict__ flag){
  const int i = blockIdx.x * 256 + threadIdx.x;
  if (i >= 4096*29) return;
  const int t = i / 29, c = i - t * 29;
  float s = b2f(bias[c]);
#pragma unroll
  for (int z = 0; z < 8; ++z) s += part[((size_t)z * 4096 + t) * 32 + c];
  if (*flag) ((float*)dst)[i] = s;
  else       ((us*)dst)[i] = f2b(s);
}

// ---------------------------------------------------------------------------
// [R,C] -> bf16 [Cp,R] transpose; src fp32 (flag=1) or bf16 (flag=0).
// ---------------------------------------------------------------------------
__global__ void transpose_any(const void* __restrict__ src_, us* __restrict__ dst,
                              int R, int C, long long smat, long long dmat,
                              const int* __restrict__ flag)
{
  const int f32 = *flag;
  dst += (size_t)blockIdx.z * dmat;
  __shared__ us tile[32][33];
  const int c0 = blockIdx.x * 32, r0 = blockIdx.y * 32;
  const int tx = threadIdx.x & 31, ty = threadIdx.x >> 5;  // 32x8
#pragma unroll
  for (int i = 0; i < 4; ++i){
    const int r = r0 + ty + i*8, c = c0 + tx;
    const size_t idx = (size_t)blockIdx.z * smat + (size_t)r * C + c;
    us v = 0;
    if (c < C){
      if (f32) v = f2b(((const float*)src_)[idx]);
      else     v = ((const us*)src_)[idx];
    }
    tile[ty + i*8][tx] = v;
  }
  __syncthreads();
#pragma unroll
  for (int i = 0; i < 4; ++i){
    const int dr = c0 + ty + i*8;
    dst[(size_t)dr * R + r0 + tx] = tile[tx][ty + i*8];
  }
}

__global__ void cvt_any_bf(const void* __restrict__ src, us* __restrict__ dst, int n,
                           const int* __restrict__ flag){
  const int i = (blockIdx.x * 256 + threadIdx.x) * 4;
  if (i >= n) return;
  s16x4 o;
  if (*flag){
    f32x4 v = *reinterpret_cast<const f32x4*>((const float*)src + i);
#pragma unroll
    for (int k = 0; k < 4; ++k) o[k] = (short)f2b(v[k]);
  } else {
    o = *reinterpret_cast<const s16x4*>((const us*)src + i);
  }
  *reinterpret_cast<s16x4*>(dst + i) = o;
}

// ---------------------------------------------------------------------------
// Router fidelity path (all fp32): M = Wproj @ Wg [512,8]; logits = x @ M.
// ---------------------------------------------------------------------------
__global__ void compose_router(const void* __restrict__ Wproj, const void* __restrict__ Wg,
                               float* __restrict__ M, const int* __restrict__ flag)
{
  const int f32 = *flag;
  const int wave = threadIdx.x >> 6, lane = threadIdx.x & 63;
  const int d = blockIdx.x * 4 + wave;
  float acc[8] = {0,0,0,0,0,0,0,0};
  for (int n = lane; n < 1024; n += 64){
    float wp;
    if (f32) wp = ((const float*)Wproj)[(size_t)d * 1024 + n];
    else     wp = b2f(((const us*)Wproj)[(size_t)d * 1024 + n]);
    if (f32){
      const float* wg = (const float*)Wg + (size_t)n * 8;
#pragma unroll
      for (int e = 0; e < 8; ++e) acc[e] += wp * wg[e];
    } else {
      const s16x8 wg = *reinterpret_cast<const s16x8*>((const us*)Wg + (size_t)n * 8);
#pragma unroll
      for (int e = 0; e < 8; ++e) acc[e] += wp * b2f((us)wg[e]);
    }
  }
#pragma unroll
  for (int e = 0; e < 8; ++e){
    float v = acc[e];
    for (int off = 32; off > 0; off >>= 1) v += __shfl_down(v, off);
    if (lane == 0) M[(size_t)d * 8 + e] = v;
  }
}

__global__ void router2(const void* __restrict__ x, const float* __restrict__ M,
                        int* __restrict__ eidx, float* __restrict__ gates,
                        const int* __restrict__ flag)
{
  const int f32 = *flag;
  const int wave = threadIdx.x >> 6, lane = threadIdx.x & 63;
  const int t = blockIdx.x * 4 + wave;
  float l[8] = {0,0,0,0,0,0,0,0};
  for (int d = lane; d < 512; d += 64){
    float xv;
    if (f32) xv = ((const float*)x)[(size_t)t * 512 + d];
    else     xv = b2f(((const us*)x)[(size_t)t * 512 + d]);
    const float* mr = M + (size_t)d * 8;
#pragma unroll
    for (int e = 0; e < 8; ++e) l[e] += xv * mr[e];
  }
#pragma unroll
  for (int e = 0; e < 8; ++e){
    float v = l[e];
    for (int off = 32; off > 0; off >>= 1) v += __shfl_down(v, off);
    l[e] = v;
  }
  if (lane == 0){
    int e0 = 0; float v0 = l[0];
#pragma unroll
    for (int e = 1; e < 8; ++e) if (l[e] > v0){ v0 = l[e]; e0 = e; }
    int e1 = (e0 == 0) ? 1 : 0; float v1 = l[e1];
#pragma unroll
    for (int e = 0; e < 8; ++e) if (e != e0 && l[e] > v1){ v1 = l[e]; e1 = e; }
    const float g1 = 1.f / (1.f + __expf(v0 - v1));
    eidx[t*2] = e0;  eidx[t*2+1] = e1;
    gates[t*2] = 1.f - g1; gates[t*2+1] = g1;
  }
}

__global__ void hist_kernel(const int* __restrict__ eidx, int* __restrict__ counts){
  __shared__ int lh[8];
  if (threadIdx.x < 8) lh[threadIdx.x] = 0;
  __syncthreads();
  const int i = blockIdx.x * 256 + threadIdx.x;
  atomicAdd(&lh[eidx[i]], 1);
  __syncthreads();
  if (threadIdx.x < 8) atomicAdd(&counts[threadIdx.x], lh[threadIdx.x]);
}

__global__ void scan_kernel(const int* __restrict__ counts, int* __restrict__ offsets){
  if (threadIdx.x == 0){
    int s = 0;
    for (int e = 0; e < 8; ++e){ offsets[e] = s; s += counts[e]; }
    offsets[8] = s;
  }
}

__global__ void fill_kernel(const int* __restrict__ eidx, const int* __restrict__ offsets,
                            int* __restrict__ fillg, int* __restrict__ pos_tk,
                            int* __restrict__ tok_of_pos){
  __shared__ int lh[8];
  __shared__ int lbase[8];
  if (threadIdx.x < 8) lh[threadIdx.x] = 0;
  __syncthreads();
  const int i = blockIdx.x * 256 + threadIdx.x;  // i = t*2 + k
  const int e = eidx[i];
  const int r = atomicAdd(&lh[e], 1);
  __syncthreads();
  if (threadIdx.x < 8) lbase[threadIdx.x] = atomicAdd(&fillg[threadIdx.x], lh[threadIdx.x]);
  __syncthreads();
  const int pos = offsets[e] + lbase[e] + r;
  pos_tk[i] = pos;
  tok_of_pos[pos] = i >> 1;
}

__global__ void combine_kernel(const float* __restrict__ eo, const float* __restrict__ shr,
                               const int* __restrict__ pos_tk, const float* __restrict__ gates,
                               us* __restrict__ comb){
  const int t = blockIdx.x;
  const int c = threadIdx.x * 4;
  const int p0 = pos_tk[t*2], p1 = pos_tk[t*2+1];
  const float g0 = gates[t*2], g1 = gates[t*2+1];
  f32x4 a = *reinterpret_cast<const f32x4*>(eo + (size_t)p0 * 1024 + c);
  f32x4 b = *reinterpret_cast<const f32x4*>(eo + (size_t)p1 * 1024 + c);
  f32x4 s = *reinterpret_cast<const f32x4*>(shr + (size_t)t * 1024 + c);
  s16x4 o;
#pragma unroll
  for (int k = 0; k < 4; ++k) o[k] = (short)f2b(g0 * a[k] + g1 * b[k] + s[k]);
  *reinterpret_cast<s16x4*>(comb + (size_t)t * 1024 + c) = o;
}

// ---------------------------------------------------------------------------
extern "C" void kernel_launch(void* const* d_in, const int* in_sizes, int n_in,
                              void* d_out, int out_size, void* d_ws, size_t ws_size,
                              hipStream_t stream)
{
  const void* x      = d_in[0];
  const void* Wproj  = d_in[1];
  const us*   bproj  = (const us*)d_in[2];   // zeros
  const void* Wg     = d_in[3];
  const void* W1     = d_in[4];
  const us*   b1     = (const us*)d_in[5];   // zeros
  const void* W2     = d_in[6];
  const us*   b2     = (const us*)d_in[7];   // zeros
  const void* sg_w   = d_in[8];
  const us*   sg_b   = (const us*)d_in[9];   // zeros
  const void* su_w   = d_in[10];
  const us*   su_b   = (const us*)d_in[11];  // zeros
  const void* sd_w   = d_in[12];
  const us*   sd_b   = (const us*)d_in[13];  // zeros
  const void* m1_w   = d_in[14];
  const us*   m1_b   = (const us*)d_in[15];  // zeros
  const void* m2_w   = d_in[16];
  const us*   m2_b   = (const us*)d_in[17];  // zeros
  const void* head_w = d_in[18];
  const us*   head_b = (const us*)d_in[19];  // zeros

  char* ws = (char*)d_ws;
  size_t off = 0;
  auto take = [&](size_t bytes) -> char* {
    char* p = ws + off; off += (bytes + 255) & ~(size_t)255; return p;
  };
  us* wprojT = (us*)take(1024ULL*512*2);
  us* w1T    = (us*)take(8ULL*2048*1024*2);
  us* w2T    = (us*)take(8ULL*1024*2048*2);
  us* sgT    = (us*)take(4096ULL*1024*2);
  us* suT    = (us*)take(4096ULL*1024*2);
  us* sdT    = (us*)take(1024ULL*4096*2);
  us* m1T    = (us*)take(2048ULL*1024*2);
  us* m2T    = (us*)take(2048ULL*2048*2);
  us* headT  = (us*)take(128ULL*2048*2);
  us* xb     = (us*)take(4096ULL*512*2);
  us* pbf    = (us*)take(4096ULL*1024*2);
  float* Mrt = (float*)take(512ULL*8*4);
  char* bufA = take(33554432);   // h -> hid2
  char* bufB = take(33554432);   // eo(fp32)
  char* bufC = take(33554432);   // s_in -> [combined | hid1]
  float* shrF  = (float*)take(4096ULL*1024*4);
  float* houtP = (float*)take(8ULL*4096*32*4);
  int* ctrl   = (int*)take(256); // counts[8], fill[8], offsets[9], flag @28
  int* eidx   = (int*)take(8192*4);
  float* gbuf = (float*)take(8192*4);
  int* postk  = (int*)take(8192*4);
  int* tokpos = (int*)take(8192*4);
  int* counts  = ctrl;
  int* fill    = ctrl + 8;
  int* offs    = ctrl + 16;
  int* dflag   = ctrl + 28;

  us* comb = (us*)bufC;
  us* hid1 = (us*)(bufC + 8388608);
  us* hid2 = (us*)bufA;

  const dim3 T(256);

  // --- dtype detect ---
  detect_kernel<<<dim3(1), T, 0, stream>>>((const unsigned*)x, dflag);

  // --- routing in full fp32: M = Wproj@Wg, logits = x@M ---
  hipMemsetAsync(ctrl, 0, 64, stream);   // counts + fill (flag untouched)
  compose_router<<<dim3(128), T, 0, stream>>>(Wproj, Wg, Mrt, dflag);
  router2<<<dim3(1024), T, 0, stream>>>(x, Mrt, eidx, gbuf, dflag);
  hist_kernel<<<dim3(32), T, 0, stream>>>(eidx, counts);
  scan_kernel<<<dim3(1), dim3(64), 0, stream>>>(counts, offs);
  fill_kernel<<<dim3(32), T, 0, stream>>>(eidx, offs, fill, postk, tokpos);

  // --- weight transposes ([R,C] -> bf16 [Cp,R]) ---
  transpose_any<<<dim3(32, 16, 1), T, 0, stream>>>(Wproj, wprojT, 512, 1024, 0, 0, dflag);
  transpose_any<<<dim3(64, 32, 8), T, 0, stream>>>(W1, w1T, 1024, 2048, 1024LL*2048, 2048LL*1024, dflag);
  transpose_any<<<dim3(32, 64, 8), T, 0, stream>>>(W2, w2T, 2048, 1024, 2048LL*1024, 1024LL*2048, dflag);
  transpose_any<<<dim3(128, 32, 1), T, 0, stream>>>(sg_w, sgT, 1024, 4096, 0, 0, dflag);
  transpose_any<<<dim3(128, 32, 1), T, 0, stream>>>(su_w, suT, 1024, 4096, 0, 0, dflag);
  transpose_any<<<dim3(32, 128, 1), T, 0, stream>>>(sd_w, sdT, 4096, 1024, 0, 0, dflag);
  transpose_any<<<dim3(64, 32, 1), T, 0, stream>>>(m1_w, m1T, 1024, 2048, 0, 0, dflag);
  transpose_any<<<dim3(64, 64, 1), T, 0, stream>>>(m2_w, m2T, 2048, 2048, 0, 0, dflag);
  transpose_any<<<dim3(4, 64, 1), T, 0, stream>>>(head_w, headT, 2048, 29, 0, 0, dflag);

  // --- x -> bf16, input projection -> bf16 p ---
  cvt_any_bf<<<dim3(2048), T, 0, stream>>>(x, xb, 4096*512, dflag);
  gemm_plain<true,false><<<dim3(8, 32), T, 0, stream>>>(xb, 512, wprojT, 512, pbf, 1024, bproj, 4096, 1024, 512, 1024);

  // --- shared experts: fused SwiGLU up (sg+su in one pass), then down ---
  gemm_sgsu<<<dim3(32, 32), T, 0, stream>>>(pbf, sgT, suT, sg_b, su_b, (us*)bufC);
  gemm_plain<false,false><<<dim3(8, 32), T, 0, stream>>>((us*)bufC, 4096, sdT, 4096, shrF, 1024, sd_b, 4096, 1024, 4096, 1024);

  // --- routed experts (top-2 grouped GEMMs over position space) ---
  gemm_group<true,true ><<<dim3(16, 64, 8), T, 0, stream>>>(pbf, 1024, tokpos, offs, w1T, bufA, 2048, b1, 2048, 1024);
  gemm_group<false,false><<<dim3(8, 64, 8), T, 0, stream>>>((us*)bufA, 2048, nullptr, offs, w2T, bufB, 1024, b2, 1024, 2048);
  combine_kernel<<<dim3(4096), T, 0, stream>>>((float*)bufB, shrF, postk, gbuf, comb);

  // --- output MLP + head (head K-split x8 + reduce) ---
  gemm_plain<true,true ><<<dim3(16, 32), T, 0, stream>>>(comb, 1024, m1T, 1024, hid1, 2048, m1_b, 4096, 2048, 1024, 2048);
  gemm_plain<true,false><<<dim3(16, 32), T, 0, stream>>>(hid1, 2048, m2T, 2048, hid2, 2048, m2_b, 4096, 2048, 2048, 2048);
  gemm_head<<<dim3(1, 32, 8), T, 0, stream>>>(hid2, headT, houtP);
  reduce_head<<<dim3(464), T, 0, stream>>>(houtP, head_b, d_out, dflag);

  (void)in_sizes; (void)n_in; (void)out_size; (void)ws_size;
}

// Round 6
// 724.032 us; speedup vs baseline: 1.3127x; 1.0491x over previous
//
#include <hip/hip_runtime.h>
#include <hip/hip_bf16.h>
#include <cstdint>

typedef unsigned short us;
typedef __attribute__((ext_vector_type(4))) float f32x4;
typedef __attribute__((ext_vector_type(8))) short bf16x8;
typedef __attribute__((ext_vector_type(4))) short s16x4;
typedef __attribute__((ext_vector_type(8))) short s16x8;

__device__ __forceinline__ float b2f(us s){
  union { float f; unsigned u; } x; x.u = ((unsigned)s) << 16; return x.f;
}
__device__ __forceinline__ us f2b(float f){
  union { float f; unsigned u; } x; x.f = f;
  unsigned r = x.u + 0x7FFFu + ((x.u >> 16) & 1u);
  return (us)(r >> 16);
}

#define GLDS16(gp, lp) __builtin_amdgcn_global_load_lds( \
    (const __attribute__((address_space(1))) void*)(gp), \
    (__attribute__((address_space(3))) void*)(lp), 16, 0, 0)

// ---------------------------------------------------------------------------
// XCD-aware swizzle: workgroup->XCD is lin%8 round-robin; remap so each XCD
// owns a compact bm x bn rectangle (round-4 FETCH=135MB -> round-5 ~49MB).
// Valid for gy==32, gx even >=8. Identity otherwise.
// ---------------------------------------------------------------------------
__device__ __forceinline__ void xcd_swizzle(int& bm, int& bn){
  const int gx = gridDim.x;
  if (gridDim.y == 32 && (gx & 1) == 0 && gx >= 8){
    const int lin = blockIdx.y * gx + blockIdx.x;
    const int xcd = lin & 7, r = lin >> 3;
    bm = (xcd & 3) * 8 + (r & 7);
    bn = (xcd >> 2) * (gx >> 1) + (r >> 3);
  } else { bm = blockIdx.y; bn = blockIdx.x; }
}

// ---------------------------------------------------------------------------
// dtype detector: flag=1 -> inputs fp32 (round-3..5 evidence), 0 -> bf16.
// ---------------------------------------------------------------------------
__global__ void detect_kernel(const unsigned* __restrict__ xw, int* __restrict__ flag){
  __shared__ int cnt;
  if (threadIdx.x == 0) cnt = 0;
  __syncthreads();
  int c = 0;
  for (int i = threadIdx.x; i < 1024; i += 256){
    const unsigned e = (xw[i] >> 7) & 0xFF;
    if (e >= 100 && e <= 140) ++c;
  }
  atomicAdd(&cnt, c);
  __syncthreads();
  if (threadIdx.x == 0) *flag = (cnt < 512) ? 1 : 0;
}

// ---------------------------------------------------------------------------
// Plain GEMM with optional K-split: C[M,N] = A[M,K]@BT[N,K]^T (+bias)(+silu).
// 128x128 tile, BK=32, 4 waves, mfma 16x16x32 bf16, glds16, XCD swizzle.
// blockIdx.z selects K-range [z*Ksplit, (z+1)*Ksplit) and partial plane z.
// ---------------------------------------------------------------------------
template<bool OUT_BF16, bool SILU>
__global__ __launch_bounds__(256, 2)
void gemm_plain(const us* __restrict__ A, int lda,
                const us* __restrict__ BT, int ldb,
                void* __restrict__ Cout_, int ldc,
                const us* __restrict__ bias,
                int M, int N, int Nvalid, int Ksplit)
{
  __shared__ us As[128*32];
  __shared__ us Bs[128*32];
  int bmi, bni; xcd_swizzle(bmi, bni);
  const int bm = bmi * 128, bn = bni * 128;
  const int tid = threadIdx.x, wave = tid >> 6, lane = tid & 63;
  const int llo = lane & 15, lhi = lane >> 4;
  char* Cout = (char*)Cout_ + (size_t)blockIdx.z * M * ldc * (OUT_BF16 ? 2 : 4);
  const int kbeg = blockIdx.z * Ksplit, kend = kbeg + Ksplit;

  const us* aP[2]; const us* bP[2]; us* lA[2]; us* lB[2];
#pragma unroll
  for (int s = 0; s < 2; ++s){
    const int chunk = s*256 + wave*64 + lane;
    const int r = chunk >> 2, cc = chunk & 3;
    aP[s] = A  + (size_t)(bm + r) * lda + cc*8;
    bP[s] = BT + (size_t)(bn + r) * ldb + cc*8;
    lA[s] = As + (size_t)(s*256 + wave*64) * 8;  // wave-uniform base
    lB[s] = Bs + (size_t)(s*256 + wave*64) * 8;
  }

  f32x4 acc[4][4] = {};
  const int waveM = (wave >> 1) * 64, waveN = (wave & 1) * 64;

  for (int k0 = kbeg; k0 < kend; k0 += 32){
    GLDS16(aP[0] + k0, lA[0]);
    GLDS16(aP[1] + k0, lA[1]);
    GLDS16(bP[0] + k0, lB[0]);
    GLDS16(bP[1] + k0, lB[1]);
    __syncthreads();
    bf16x8 af[4], bv[4];
#pragma unroll
    for (int t = 0; t < 4; ++t){
      af[t] = *reinterpret_cast<const bf16x8*>(As + (waveM + t*16 + llo)*32 + lhi*8);
      bv[t] = *reinterpret_cast<const bf16x8*>(Bs + (waveN + t*16 + llo)*32 + lhi*8);
    }
#pragma unroll
    for (int mt = 0; mt < 4; ++mt)
#pragma unroll
      for (int nt = 0; nt < 4; ++nt)
        acc[mt][nt] = __builtin_amdgcn_mfma_f32_16x16x32_bf16(af[mt], bv[nt], acc[mt][nt], 0, 0, 0);
    __syncthreads();
  }

#pragma unroll
  for (int nt = 0; nt < 4; ++nt){
    const int col = bn + waveN + nt*16 + llo;
    float bb = 0.f;
    if (bias && col < Nvalid) bb = b2f(bias[col]);
#pragma unroll
    for (int mt = 0; mt < 4; ++mt){
      const int row0 = bm + waveM + mt*16 + lhi*4;  // C/D: col=lane&15, row=quad*4+reg
#pragma unroll
      for (int r = 0; r < 4; ++r){
        if (col < Nvalid){
          float v = acc[mt][nt][r] + bb;
          if (SILU) v = v / (1.f + __expf(-v));
          if (OUT_BF16) ((us*)Cout)[(size_t)(row0 + r) * ldc + col] = f2b(v);
          else          ((float*)Cout)[(size_t)(row0 + r) * ldc + col] = v;
        }
      }
    }
  }
}

// ---------------------------------------------------------------------------
// Fused shared-expert SwiGLU up: s_in = silu(p@sg+b)*(p@su+b). 4096/4096/1024.
// ---------------------------------------------------------------------------
__global__ __launch_bounds__(256, 2)
void gemm_sgsu(const us* __restrict__ A, const us* __restrict__ B1T,
               const us* __restrict__ B2T, const us* __restrict__ bias1,
               const us* __restrict__ bias2, us* __restrict__ Cout)
{
  __shared__ us As[128*32];
  __shared__ us B1s[128*32];
  __shared__ us B2s[128*32];
  int bmi, bni; xcd_swizzle(bmi, bni);
  const int bm = bmi * 128, bn = bni * 128;
  const int tid = threadIdx.x, wave = tid >> 6, lane = tid & 63;
  const int llo = lane & 15, lhi = lane >> 4;

  const us* aP[2]; const us* b1P[2]; const us* b2P[2];
  us* lA[2]; us* lB1[2]; us* lB2[2];
#pragma unroll
  for (int s = 0; s < 2; ++s){
    const int chunk = s*256 + wave*64 + lane;
    const int r = chunk >> 2, cc = chunk & 3;
    aP[s]  = A   + (size_t)(bm + r) * 1024 + cc*8;
    b1P[s] = B1T + (size_t)(bn + r) * 1024 + cc*8;
    b2P[s] = B2T + (size_t)(bn + r) * 1024 + cc*8;
    lA[s]  = As  + (size_t)(s*256 + wave*64) * 8;
    lB1[s] = B1s + (size_t)(s*256 + wave*64) * 8;
    lB2[s] = B2s + (size_t)(s*256 + wave*64) * 8;
  }

  f32x4 acc1[4][4] = {};
  f32x4 acc2[4][4] = {};
  const int waveM = (wave >> 1) * 64, waveN = (wave & 1) * 64;

  for (int k0 = 0; k0 < 1024; k0 += 32){
    GLDS16(aP[0] + k0, lA[0]);
    GLDS16(aP[1] + k0, lA[1]);
    GLDS16(b1P[0] + k0, lB1[0]);
    GLDS16(b1P[1] + k0, lB1[1]);
    GLDS16(b2P[0] + k0, lB2[0]);
    GLDS16(b2P[1] + k0, lB2[1]);
    __syncthreads();
    bf16x8 af[4], b1v[4], b2v[4];
#pragma unroll
    for (int t = 0; t < 4; ++t){
      af[t]  = *reinterpret_cast<const bf16x8*>(As  + (waveM + t*16 + llo)*32 + lhi*8);
      b1v[t] = *reinterpret_cast<const bf16x8*>(B1s + (waveN + t*16 + llo)*32 + lhi*8);
      b2v[t] = *reinterpret_cast<const bf16x8*>(B2s + (waveN + t*16 + llo)*32 + lhi*8);
    }
#pragma unroll
    for (int mt = 0; mt < 4; ++mt)
#pragma unroll
      for (int nt = 0; nt < 4; ++nt){
        acc1[mt][nt] = __builtin_amdgcn_mfma_f32_16x16x32_bf16(af[mt], b1v[nt], acc1[mt][nt], 0, 0, 0);
        acc2[mt][nt] = __builtin_amdgcn_mfma_f32_16x16x32_bf16(af[mt], b2v[nt], acc2[mt][nt], 0, 0, 0);
      }
    __syncthreads();
  }

#pragma unroll
  for (int nt = 0; nt < 4; ++nt){
    const int col = bn + waveN + nt*16 + llo;
    const float bb1 = b2f(bias1[col]);
    const float bb2 = b2f(bias2[col]);
#pragma unroll
    for (int mt = 0; mt < 4; ++mt){
      const int row0 = bm + waveM + mt*16 + lhi*4;
#pragma unroll
      for (int r = 0; r < 4; ++r){
        const float g = acc1[mt][nt][r] + bb1;
        const float v = (g / (1.f + __expf(-g))) * (acc2[mt][nt][r] + bb2);
        Cout[(size_t)(row0 + r) * 4096 + col] = f2b(v);
      }
    }
  }
}

// ---------------------------------------------------------------------------
// Grouped (MoE) GEMM over position space. blockIdx.z = expert.
// ---------------------------------------------------------------------------
template<bool OUT_BF16, bool SILU>
__global__ __launch_bounds__(256, 2)
void gemm_group(const us* __restrict__ Abase, int lda,
                const int* __restrict__ rowmap,
                const int* __restrict__ offsets,   // [E+1], offsets[E]=8192
                const us* __restrict__ BTbase,     // [E][N][K]
                void* __restrict__ Cout, int ldc,
                const us* __restrict__ biasbase,   // [E][N]
                int N, int K)
{
  const int e   = blockIdx.z;
  const int off = offsets[e];
  const int Te  = offsets[e + 1] - off;
  const int bmL = blockIdx.y * 128;
  if (bmL >= Te) return;

  __shared__ us As[128*32];
  __shared__ us Bs[128*32];
  const us* BT   = BTbase  + (size_t)e * N * K;
  const us* bias = biasbase + (size_t)e * N;
  const int bn = blockIdx.x * 128;
  const int tid = threadIdx.x, wave = tid >> 6, lane = tid & 63;
  const int llo = lane & 15, lhi = lane >> 4;

  const us* aP[2]; const us* bP[2]; us* lA[2]; us* lB[2];
#pragma unroll
  for (int s = 0; s < 2; ++s){
    const int chunk = s*256 + wave*64 + lane;
    const int r = chunk >> 2, cc = chunk & 3;
    int pos = off + bmL + r; if (pos > 8191) pos = 8191; // OOB rows masked on store
    const int arow = rowmap ? rowmap[pos] : pos;
    aP[s] = Abase + (size_t)arow * lda + cc*8;
    bP[s] = BT + (size_t)(bn + r) * K + cc*8;
    lA[s] = As + (size_t)(s*256 + wave*64) * 8;
    lB[s] = Bs + (size_t)(s*256 + wave*64) * 8;
  }

  f32x4 acc[4][4] = {};
  const int waveM = (wave >> 1) * 64, waveN = (wave & 1) * 64;

  for (int k0 = 0; k0 < K; k0 += 32){
    GLDS16(aP[0] + k0, lA[0]);
    GLDS16(aP[1] + k0, lA[1]);
    GLDS16(bP[0] + k0, lB[0]);
    GLDS16(bP[1] + k0, lB[1]);
    __syncthreads();
    bf16x8 af[4], bv[4];
#pragma unroll
    for (int t = 0; t < 4; ++t){
      af[t] = *reinterpret_cast<const bf16x8*>(As + (waveM + t*16 + llo)*32 + lhi*8);
      bv[t] = *reinterpret_cast<const bf16x8*>(Bs + (waveN + t*16 + llo)*32 + lhi*8);
    }
#pragma unroll
    for (int mt = 0; mt < 4; ++mt)
#pragma unroll
      for (int nt = 0; nt < 4; ++nt)
        acc[mt][nt] = __builtin_amdgcn_mfma_f32_16x16x32_bf16(af[mt], bv[nt], acc[mt][nt], 0, 0, 0);
    __syncthreads();
  }

#pragma unroll
  for (int nt = 0; nt < 4; ++nt){
    const int col = bn + waveN + nt*16 + llo;
    const float bb = b2f(bias[col]);
#pragma unroll
    for (int mt = 0; mt < 4; ++mt){
      const int localBase = bmL + waveM + mt*16 + lhi*4;
#pragma unroll
      for (int r = 0; r < 4; ++r){
        const int local = localBase + r;
        if (local < Te){
          float v = acc[mt][nt][r] + bb;
          if (SILU) v = v / (1.f + __expf(-v));
          const size_t row = (size_t)(off + local);
          if (OUT_BF16) ((us*)Cout)[row * ldc + col] = f2b(v);
          else          ((float*)Cout)[row * ldc + col] = v;
        }
      }
    }
  }
}

// ---------------------------------------------------------------------------
// Head GEMM, K-split x8: partials[z][4096][32] fp32.
// ---------------------------------------------------------------------------
__global__ __launch_bounds__(256, 2)
void gemm_head(const us* __restrict__ A, const us* __restrict__ BT,
               float* __restrict__ Cpart)
{
  __shared__ us As[128*32];
  __shared__ us Bs[128*32];
  const int bm = blockIdx.y * 128;
  const int koff = blockIdx.z * 256;
  const int tid = threadIdx.x, wave = tid >> 6, lane = tid & 63;
  const int llo = lane & 15, lhi = lane >> 4;

  const us* aP[2]; const us* bP[2]; us* lA[2]; us* lB[2];
#pragma unroll
  for (int s = 0; s < 2; ++s){
    const int chunk = s*256 + wave*64 + lane;
    const int r = chunk >> 2, cc = chunk & 3;
    aP[s] = A  + (size_t)(bm + r) * 2048 + koff + cc*8;
    bP[s] = BT + (size_t)r * 2048 + koff + cc*8;
    lA[s] = As + (size_t)(s*256 + wave*64) * 8;
    lB[s] = Bs + (size_t)(s*256 + wave*64) * 8;
  }

  f32x4 acc[4][4] = {};
  const int waveM = (wave >> 1) * 64, waveN = (wave & 1) * 64;

  for (int k0 = 0; k0 < 256; k0 += 32){
    GLDS16(aP[0] + k0, lA[0]);
    GLDS16(aP[1] + k0, lA[1]);
    GLDS16(bP[0] + k0, lB[0]);
    GLDS16(bP[1] + k0, lB[1]);
    __syncthreads();
    bf16x8 af[4], bv[4];
#pragma unroll
    for (int t = 0; t < 4; ++t){
      af[t] = *reinterpret_cast<const bf16x8*>(As + (waveM + t*16 + llo)*32 + lhi*8);
      bv[t] = *reinterpret_cast<const bf16x8*>(Bs + (waveN + t*16 + llo)*32 + lhi*8);
    }
#pragma unroll
    for (int mt = 0; mt < 4; ++mt)
#pragma unroll
      for (int nt = 0; nt < 4; ++nt)
        acc[mt][nt] = __builtin_amdgcn_mfma_f32_16x16x32_bf16(af[mt], bv[nt], acc[mt][nt], 0, 0, 0);
    __syncthreads();
  }

  float* out = Cpart + (size_t)blockIdx.z * 4096 * 32;
#pragma unroll
  for (int nt = 0; nt < 4; ++nt){
    const int col = waveN + nt*16 + llo;
    if (col >= 29) continue;
#pragma unroll
    for (int mt = 0; mt < 4; ++mt){
      const int row0 = bm + waveM + mt*16 + lhi*4;
#pragma unroll
      for (int r = 0; r < 4; ++r)
        out[(size_t)(row0 + r) * 32 + col] = acc[mt][nt][r];
    }
  }
}

__global__ void reduce_head(const float* __restrict__ part, const us* __restrict__ bias,
                            void* __restrict__ dst, const int* __restrict__ flag){
  const int i = blockIdx.x * 256 + threadIdx.x;
  if (i >= 4096*29) return;
  const int t = i / 29, c = i - t * 29;
  float s = b2f(bias[c]);
#pragma unroll
  for (int z = 0; z < 8; ++z) s += part[((size_t)z * 4096 + t) * 32 + c];
  if (*flag) ((float*)dst)[i] = s;
  else       ((us*)dst)[i] = f2b(s);
}

// ---------------------------------------------------------------------------
// Batched transpose: all 9 weight matrices in ONE dispatch (round-6: ~27
// dispatches had ~100us of launch gaps). Each block = one 32x32 tile.
// ---------------------------------------------------------------------------
struct TransDesc {
  const void* src; us* dst;
  int R, C, tx, ty, prefix;     // tx,ty = tiles per matrix; prefix = first tile id
  long long smat, dmat;         // per-z strides (elements)
};
struct TransTable { TransDesc d[9]; };

__global__ void transpose_batched(TransTable tt, const int* __restrict__ flag){
  const int f32 = *flag;
  const int bid = blockIdx.x;
  int m = 0;
#pragma unroll
  for (int i = 1; i < 9; ++i) if (bid >= tt.d[i].prefix) m = i;
  const TransDesc dd = tt.d[m];
  const int local = bid - dd.prefix;
  const int per = dd.tx * dd.ty;
  const int z = local / per;
  const int rem = local - z * per;
  const int tyi = rem / dd.tx, txi = rem - tyi * dd.tx;

  const int c0 = txi * 32, r0 = tyi * 32;
  __shared__ us tile[32][33];
  const int tx = threadIdx.x & 31, ty = threadIdx.x >> 5;  // 32x8
#pragma unroll
  for (int i = 0; i < 4; ++i){
    const int r = r0 + ty + i*8, c = c0 + tx;
    const size_t idx = (size_t)z * dd.smat + (size_t)r * dd.C + c;
    us v = 0;
    if (c < dd.C){
      if (f32) v = f2b(((const float*)dd.src)[idx]);
      else     v = ((const us*)dd.src)[idx];
    }
    tile[ty + i*8][tx] = v;
  }
  __syncthreads();
  us* dst = dd.dst + (size_t)z * dd.dmat;
#pragma unroll
  for (int i = 0; i < 4; ++i){
    const int dr = c0 + ty + i*8;
    dst[(size_t)dr * dd.R + r0 + tx] = tile[tx][ty + i*8];
  }
}

__global__ void cvt_any_bf(const void* __restrict__ src, us* __restrict__ dst, int n,
                           const int* __restrict__ flag){
  const int i = (blockIdx.x * 256 + threadIdx.x) * 4;
  if (i >= n) return;
  s16x4 o;
  if (*flag){
    f32x4 v = *reinterpret_cast<const f32x4*>((const float*)src + i);
#pragma unroll
    for (int k = 0; k < 4; ++k) o[k] = (short)f2b(v[k]);
  } else {
    o = *reinterpret_cast<const s16x4*>((const us*)src + i);
  }
  *reinterpret_cast<s16x4*>(dst + i) = o;
}

// ---------------------------------------------------------------------------
// Router fidelity path (all fp32): M = Wproj @ Wg [512,8]; logits = x @ M.
// ---------------------------------------------------------------------------
__global__ void compose_router(const void* __restrict__ Wproj, const void* __restrict__ Wg,
                               float* __restrict__ M, const int* __restrict__ flag)
{
  const int f32 = *flag;
  const int wave = threadIdx.x >> 6, lane = threadIdx.x & 63;
  const int d = blockIdx.x * 4 + wave;
  float acc[8] = {0,0,0,0,0,0,0,0};
  for (int n = lane; n < 1024; n += 64){
    float wp;
    if (f32) wp = ((const float*)Wproj)[(size_t)d * 1024 + n];
    else     wp = b2f(((const us*)Wproj)[(size_t)d * 1024 + n]);
    if (f32){
      const float* wg = (const float*)Wg + (size_t)n * 8;
#pragma unroll
      for (int e = 0; e < 8; ++e) acc[e] += wp * wg[e];
    } else {
      const s16x8 wg = *reinterpret_cast<const s16x8*>((const us*)Wg + (size_t)n * 8);
#pragma unroll
      for (int e = 0; e < 8; ++e) acc[e] += wp * b2f((us)wg[e]);
    }
  }
#pragma unroll
  for (int e = 0; e < 8; ++e){
    float v = acc[e];
    for (int off = 32; off > 0; off >>= 1) v += __shfl_down(v, off);
    if (lane == 0) M[(size_t)d * 8 + e] = v;
  }
}

__global__ void router2(const void* __restrict__ x, const float* __restrict__ M,
                        int* __restrict__ eidx, float* __restrict__ gates,
                        const int* __restrict__ flag)
{
  const int f32 = *flag;
  const int wave = threadIdx.x >> 6, lane = threadIdx.x & 63;
  const int t = blockIdx.x * 4 + wave;
  float l[8] = {0,0,0,0,0,0,0,0};
  for (int d = lane; d < 512; d += 64){
    float xv;
    if (f32) xv = ((const float*)x)[(size_t)t * 512 + d];
    else     xv = b2f(((const us*)x)[(size_t)t * 512 + d]);
    const float* mr = M + (size_t)d * 8;
#pragma unroll
    for (int e = 0; e < 8; ++e) l[e] += xv * mr[e];
  }
#pragma unroll
  for (int e = 0; e < 8; ++e){
    float v = l[e];
    for (int off = 32; off > 0; off >>= 1) v += __shfl_down(v, off);
    l[e] = v;
  }
  if (lane == 0){
    int e0 = 0; float v0 = l[0];
#pragma unroll
    for (int e = 1; e < 8; ++e) if (l[e] > v0){ v0 = l[e]; e0 = e; }
    int e1 = (e0 == 0) ? 1 : 0; float v1 = l[e1];
#pragma unroll
    for (int e = 0; e < 8; ++e) if (e != e0 && l[e] > v1){ v1 = l[e]; e1 = e; }
    const float g1 = 1.f / (1.f + __expf(v0 - v1));
    eidx[t*2] = e0;  eidx[t*2+1] = e1;
    gates[t*2] = 1.f - g1; gates[t*2+1] = g1;
  }
}

// per-block histograms -> histB[32][8]; no global atomics, no memset needed.
__global__ void hist_kernel(const int* __restrict__ eidx, int* __restrict__ histB){
  __shared__ int lh[8];
  if (threadIdx.x < 8) lh[threadIdx.x] = 0;
  __syncthreads();
  atomicAdd(&lh[eidx[blockIdx.x * 256 + threadIdx.x]], 1);
  __syncthreads();
  if (threadIdx.x < 8) histB[blockIdx.x * 8 + threadIdx.x] = lh[threadIdx.x];
}

// offsets[9] + per-block bases blockbase[32][8] (exclusive scan over histB).
__global__ void scan_kernel(const int* __restrict__ histB, int* __restrict__ offsets,
                            int* __restrict__ blockbase){
  if (threadIdx.x == 0){
    int counts[8] = {0,0,0,0,0,0,0,0};
    for (int b = 0; b < 32; ++b)
      for (int e = 0; e < 8; ++e) counts[e] += histB[b*8 + e];
    int s = 0;
    for (int e = 0; e < 8; ++e){ offsets[e] = s; s += counts[e]; }
    offsets[8] = s;
    for (int e = 0; e < 8; ++e){
      int run = offsets[e];
      for (int b = 0; b < 32; ++b){ blockbase[b*8 + e] = run; run += histB[b*8 + e]; }
    }
  }
}

// LDS rank + precomputed block base; zero global atomics.
__global__ void fill_kernel(const int* __restrict__ eidx, const int* __restrict__ blockbase,
                            int* __restrict__ pos_tk, int* __restrict__ tok_of_pos){
  __shared__ int lh[8];
  if (threadIdx.x < 8) lh[threadIdx.x] = 0;
  __syncthreads();
  const int i = blockIdx.x * 256 + threadIdx.x;  // i = t*2 + k
  const int e = eidx[i];
  const int r = atomicAdd(&lh[e], 1);
  const int pos = blockbase[blockIdx.x * 8 + e] + r;
  pos_tk[i] = pos;
  tok_of_pos[pos] = i >> 1;
}

// combine: eo now bf16; shared partials = 2 fp32 K-split planes.
__global__ void combine_kernel(const us* __restrict__ eo, const float* __restrict__ shr,
                               const int* __restrict__ pos_tk, const float* __restrict__ gates,
                               us* __restrict__ comb){
  const int t = blockIdx.x;
  const int c = threadIdx.x * 4;
  const int p0 = pos_tk[t*2], p1 = pos_tk[t*2+1];
  const float g0 = gates[t*2], g1 = gates[t*2+1];
  s16x4 a = *reinterpret_cast<const s16x4*>(eo + (size_t)p0 * 1024 + c);
  s16x4 b = *reinterpret_cast<const s16x4*>(eo + (size_t)p1 * 1024 + c);
  f32x4 s0 = *reinterpret_cast<const f32x4*>(shr + (size_t)t * 1024 + c);
  f32x4 s1 = *reinterpret_cast<const f32x4*>(shr + 4096ULL*1024 + (size_t)t * 1024 + c);
  s16x4 o;
#pragma unroll
  for (int k = 0; k < 4; ++k)
    o[k] = (short)f2b(g0 * b2f((us)a[k]) + g1 * b2f((us)b[k]) + s0[k] + s1[k]);
  *reinterpret_cast<s16x4*>(comb + (size_t)t * 1024 + c) = o;
}

// ---------------------------------------------------------------------------
extern "C" void kernel_launch(void* const* d_in, const int* in_sizes, int n_in,
                              void* d_out, int out_size, void* d_ws, size_t ws_size,
                              hipStream_t stream)
{
  const void* x      = d_in[0];
  const void* Wproj  = d_in[1];
  const us*   bproj  = (const us*)d_in[2];   // zeros
  const void* Wg     = d_in[3];
  const void* W1     = d_in[4];
  const us*   b1     = (const us*)d_in[5];   // zeros
  const void* W2     = d_in[6];
  const us*   b2     = (const us*)d_in[7];   // zeros
  const void* sg_w   = d_in[8];
  const us*   sg_b   = (const us*)d_in[9];   // zeros
  const void* su_w   = d_in[10];
  const us*   su_b   = (const us*)d_in[11];  // zeros
  const void* sd_w   = d_in[12];
  const us*   sd_b   = (const us*)d_in[13];  // zeros
  const void* m1_w   = d_in[14];
  const us*   m1_b   = (const us*)d_in[15];  // zeros
  const void* m2_w   = d_in[16];
  const us*   m2_b   = (const us*)d_in[17];  // zeros
  const void* head_w = d_in[18];
  const us*   head_b = (const us*)d_in[19];  // zeros

  char* ws = (char*)d_ws;
  size_t off = 0;
  auto take = [&](size_t bytes) -> char* {
    char* p = ws + off; off += (bytes + 255) & ~(size_t)255; return p;
  };
  us* wprojT = (us*)take(1024ULL*512*2);
  us* w1T    = (us*)take(8ULL*2048*1024*2);
  us* w2T    = (us*)take(8ULL*1024*2048*2);
  us* sgT    = (us*)take(4096ULL*1024*2);
  us* suT    = (us*)take(4096ULL*1024*2);
  us* sdT    = (us*)take(1024ULL*4096*2);
  us* m1T    = (us*)take(2048ULL*1024*2);
  us* m2T    = (us*)take(2048ULL*2048*2);
  us* headT  = (us*)take(128ULL*2048*2);
  us* xb     = (us*)take(4096ULL*512*2);
  us* pbf    = (us*)take(4096ULL*1024*2);
  float* Mrt = (float*)take(512ULL*8*4);
  char* bufA = take(33554432);   // h -> hid2
  char* bufB = take(33554432);   // eo (bf16)
  char* bufC = take(33554432);   // s_in -> [combined | hid1]
  float* shrF  = (float*)take(2ULL*4096*1024*4);  // 2 K-split planes
  float* houtP = (float*)take(8ULL*4096*32*4);
  int* ctrl   = (int*)take(256);     // offsets[9], flag @28
  int* histB  = (int*)take(32*8*4);
  int* bbase  = (int*)take(32*8*4);
  int* eidx   = (int*)take(8192*4);
  float* gbuf = (float*)take(8192*4);
  int* postk  = (int*)take(8192*4);
  int* tokpos = (int*)take(8192*4);
  int* offs   = ctrl;
  int* dflag  = ctrl + 28;

  us* comb = (us*)bufC;
  us* hid1 = (us*)(bufC + 8388608);
  us* hid2 = (us*)bufA;

  const dim3 T(256);

  // --- dtype detect ---
  detect_kernel<<<dim3(1), T, 0, stream>>>((const unsigned*)x, dflag);

  // --- all weight transposes in ONE dispatch ---
  TransTable tt;
  auto mk = [](const void* s, us* d, int R, int C, int tx, int ty, int prefix,
               long long smat, long long dmat) -> TransDesc {
    TransDesc t; t.src = s; t.dst = d; t.R = R; t.C = C; t.tx = tx; t.ty = ty;
    t.prefix = prefix; t.smat = smat; t.dmat = dmat; return t;
  };
  int pf = 0;
  tt.d[0] = mk(Wproj, wprojT, 512, 1024, 32, 16, pf, 0, 0);                  pf += 32*16;
  tt.d[1] = mk(W1, w1T, 1024, 2048, 64, 32, pf, 1024LL*2048, 2048LL*1024);   pf += 64*32*8;
  tt.d[2] = mk(W2, w2T, 2048, 1024, 32, 64, pf, 2048LL*1024, 1024LL*2048);   pf += 32*64*8;
  tt.d[3] = mk(sg_w, sgT, 1024, 4096, 128, 32, pf, 0, 0);                    pf += 128*32;
  tt.d[4] = mk(su_w, suT, 1024, 4096, 128, 32, pf, 0, 0);                    pf += 128*32;
  tt.d[5] = mk(sd_w, sdT, 4096, 1024, 32, 128, pf, 0, 0);                    pf += 32*128;
  tt.d[6] = mk(m1_w, m1T, 1024, 2048, 64, 32, pf, 0, 0);                     pf += 64*32;
  tt.d[7] = mk(m2_w, m2T, 2048, 2048, 64, 64, pf, 0, 0);                     pf += 64*64;
  tt.d[8] = mk(head_w, headT, 2048, 29, 4, 64, pf, 0, 0);                    pf += 4*64;
  transpose_batched<<<dim3(pf), T, 0, stream>>>(tt, dflag);

  // --- routing in full fp32 (no global atomics anywhere) ---
  compose_router<<<dim3(128), T, 0, stream>>>(Wproj, Wg, Mrt, dflag);
  router2<<<dim3(1024), T, 0, stream>>>(x, Mrt, eidx, gbuf, dflag);
  hist_kernel<<<dim3(32), T, 0, stream>>>(eidx, histB);
  scan_kernel<<<dim3(1), dim3(64), 0, stream>>>(histB, offs, bbase);
  fill_kernel<<<dim3(32), T, 0, stream>>>(eidx, bbase, postk, tokpos);

  // --- x -> bf16, input projection -> bf16 p ---
  cvt_any_bf<<<dim3(2048), T, 0, stream>>>(x, xb, 4096*512, dflag);
  gemm_plain<true,false><<<dim3(8, 32), T, 0, stream>>>(xb, 512, wprojT, 512, pbf, 1024, bproj, 4096, 1024, 1024, 512);

  // --- shared experts: fused SwiGLU up, then down with K-split x2 (2 blk/CU) ---
  gemm_sgsu<<<dim3(32, 32), T, 0, stream>>>(pbf, sgT, suT, sg_b, su_b, (us*)bufC);
  gemm_plain<false,false><<<dim3(8, 32, 2), T, 0, stream>>>((us*)bufC, 4096, sdT, 4096, shrF, 1024, sd_b, 4096, 1024, 1024, 2048);

  // --- routed experts (top-2 grouped GEMMs over position space) ---
  gemm_group<true,true ><<<dim3(16, 64, 8), T, 0, stream>>>(pbf, 1024, tokpos, offs, w1T, bufA, 2048, b1, 2048, 1024);
  gemm_group<true,false><<<dim3(8, 64, 8), T, 0, stream>>>((us*)bufA, 2048, nullptr, offs, w2T, bufB, 1024, b2, 1024, 2048);
  combine_kernel<<<dim3(4096), T, 0, stream>>>((us*)bufB, shrF, postk, gbuf, comb);

  // --- output MLP + head (head K-split x8 + reduce) ---
  gemm_plain<true,true ><<<dim3(16, 32), T, 0, stream>>>(comb, 1024, m1T, 1024, hid1, 2048, m1_b, 4096, 2048, 2048, 1024);
  gemm_plain<true,false><<<dim3(16, 32), T, 0, stream>>>(hid1, 2048, m2T, 2048, hid2, 2048, m2_b, 4096, 2048, 2048, 2048);
  gemm_head<<<dim3(1, 32, 8), T, 0, stream>>>(hid2, headT, houtP);
  reduce_head<<<dim3(464), T, 0, stream>>>(houtP, head_b, d_out, dflag);

  (void)in_sizes; (void)n_in; (void)out_size; (void)ws_size;
}